// Round 1
// baseline (1241.678 us; speedup 1.0000x reference)
//
#include <hip/hip_runtime.h>

#define S_LEN 2048
#define DMODEL 2048
#define NH 32
#define NKV 8
#define HD 64
#define FFN_DIM 8192

typedef __attribute__((ext_vector_type(4))) float f32x4;
typedef __attribute__((ext_vector_type(8))) short bf16x8;

#define MFMA(a, b, c) __builtin_amdgcn_mfma_f32_16x16x32_bf16(a, b, c, 0, 0, 0)

__device__ __forceinline__ ushort f2bf(float f) {
  unsigned u = __float_as_uint(f);
  unsigned r = (u + 0x7fffu + ((u >> 16) & 1u)) >> 16;
  return (ushort)r;
}
__device__ __forceinline__ float bf2f(ushort s) {
  return __uint_as_float(((unsigned)s) << 16);
}

__device__ __forceinline__ void gload16(const void* g, void* l) {
  __builtin_amdgcn_global_load_lds(
      (const __attribute__((address_space(1))) void*)g,
      (__attribute__((address_space(3))) void*)l, 16, 0, 0);
}

__device__ __forceinline__ bf16x8 cvt8(const float* p) {
  f32x4 lo = *(const f32x4*)p;
  f32x4 hi = *(const f32x4*)(p + 4);
  bf16x8 r;
#pragma unroll
  for (int i = 0; i < 4; i++) r[i] = (short)f2bf(lo[i]);
#pragma unroll
  for (int i = 0; i < 4; i++) r[4 + i] = (short)f2bf(hi[i]);
  return r;
}

// ---------------- RMSNorm: f32 in -> bf16 out ----------------
__global__ __launch_bounds__(256) void rmsnorm_k(const float* __restrict__ in,
                                                 const float* __restrict__ w,
                                                 ushort* __restrict__ out) {
  const int row = blockIdx.x;
  const int tid = threadIdx.x;
  const float* x = in + (size_t)row * DMODEL;
  f32x4 v0 = *(const f32x4*)(x + tid * 8);
  f32x4 v1 = *(const f32x4*)(x + tid * 8 + 4);
  float ss = v0[0] * v0[0] + v0[1] * v0[1] + v0[2] * v0[2] + v0[3] * v0[3] +
             v1[0] * v1[0] + v1[1] * v1[1] + v1[2] * v1[2] + v1[3] * v1[3];
#pragma unroll
  for (int off = 32; off; off >>= 1) ss += __shfl_xor(ss, off, 64);
  __shared__ float red[4];
  if ((tid & 63) == 0) red[tid >> 6] = ss;
  __syncthreads();
  float tot = red[0] + red[1] + red[2] + red[3];
  float inv = rsqrtf(tot * (1.f / DMODEL) + 1e-5f);
#pragma unroll
  for (int i = 0; i < 8; i++) {
    int c = tid * 8 + i;
    float val = (i < 4) ? v0[i] : v1[i - 4];
    out[(size_t)row * DMODEL + c] = f2bf(w[c] * val * inv);
  }
}

// ---------------- RoPE (in-place on bf16 qkv buffer) ----------------
__global__ __launch_bounds__(256) void rope_k(ushort* __restrict__ qkv,
                                              const float* __restrict__ cs,
                                              const float* __restrict__ sn) {
  int idx = blockIdx.x * 256 + threadIdx.x;
  int d = idx & 31;
  int t = idx >> 5;
  int head = t % (NH + NKV);
  int s = t / (NH + NKV);
  int col = (head < NH) ? head * HD : DMODEL + (head - NH) * HD;
  ushort* p = qkv + (size_t)s * 3072 + col;
  float lo = bf2f(p[d]), hi = bf2f(p[d + 32]);
  float c = cs[s * HD + d], si = sn[s * HD + d];
  p[d] = f2bf(lo * c - hi * si);
  p[d + 32] = f2bf(hi * c + lo * si);
}

// ---------------- GEMM: C[M,N] = A(bf16)[M,K] @ B(f32)[N,K]^T + bias ----------------
// 128x128 tile, 4 waves (2x2), BK=32, global_load_lds staging, B converted at frag read.
enum { EPI_BF16 = 0, EPI_RESID = 1, EPI_SILU = 2, EPI_MUL = 3 };

template <int EPI>
__global__ __launch_bounds__(256) void gemm_bt(
    const ushort* __restrict__ A, int lda, const float* __restrict__ B, int ldb,
    const float* __restrict__ bias, const float* __restrict__ resid, int ldr,
    ushort* __restrict__ outb, float* __restrict__ outf, int ldc, int ncol0,
    int K) {
  __shared__ __align__(16) ushort Asm[128 * 32];
  __shared__ __align__(16) float Bsm[128 * 32];
  const int tid = threadIdx.x;
  const int lane = tid & 63, wid = tid >> 6;
  const int wr = wid >> 1, wc = wid & 1;
  const int g = lane >> 4, r16 = lane & 15;
  const int m0 = blockIdx.x * 128, n0 = blockIdx.y * 128;

  const ushort* Ag = A + (size_t)m0 * lda;
  const float* Bg = B + (size_t)n0 * ldb;

  f32x4 acc[4][4];
#pragma unroll
  for (int i = 0; i < 4; i++)
#pragma unroll
    for (int j = 0; j < 4; j++) acc[i][j] = (f32x4){0, 0, 0, 0};

  for (int kt = 0; kt < K; kt += 32) {
#pragma unroll
    for (int p = 0; p < 2; ++p) {  // A tile: 8KB
      int t = (p * 4 + wid) * 64 + lane;
      int r = t >> 2, c = (t & 3) << 3;
      gload16(Ag + (size_t)r * lda + kt + c, (char*)Asm + (p * 4 + wid) * 1024);
    }
#pragma unroll
    for (int p = 0; p < 4; ++p) {  // B tile: 16KB (f32)
      int t = (p * 4 + wid) * 64 + lane;
      int r = t >> 3, c = (t & 7) << 2;
      gload16(Bg + (size_t)r * ldb + kt + c, (char*)Bsm + (p * 4 + wid) * 1024);
    }
    __syncthreads();
    bf16x8 af[4], bfr[4];
#pragma unroll
    for (int mt = 0; mt < 4; mt++)
      af[mt] = *(const bf16x8*)(Asm + (wr * 64 + mt * 16 + r16) * 32 + g * 8);
#pragma unroll
    for (int nt = 0; nt < 4; nt++)
      bfr[nt] = cvt8(Bsm + (wc * 64 + nt * 16 + r16) * 32 + g * 8);
#pragma unroll
    for (int mt = 0; mt < 4; mt++)
#pragma unroll
      for (int nt = 0; nt < 4; nt++)
        acc[mt][nt] = MFMA(af[mt], bfr[nt], acc[mt][nt]);
    __syncthreads();
  }

#pragma unroll
  for (int mt = 0; mt < 4; mt++) {
#pragma unroll
    for (int nt = 0; nt < 4; nt++) {
      int n = n0 + wc * 64 + nt * 16 + r16;
      float bia = bias[n];
#pragma unroll
      for (int reg = 0; reg < 4; reg++) {
        int m = m0 + wr * 64 + mt * 16 + g * 4 + reg;
        float v = acc[mt][nt][reg] + bia;
        if constexpr (EPI == EPI_BF16) {
          outb[(size_t)m * ldc + ncol0 + n] = f2bf(v);
        } else if constexpr (EPI == EPI_RESID) {
          outf[(size_t)m * ldc + n] = v + resid[(size_t)m * ldr + n];
        } else if constexpr (EPI == EPI_SILU) {
          float sv = v / (1.f + __expf(-v));
          outb[(size_t)m * ldc + n] = f2bf(sv);
        } else {  // EPI_MUL: v * existing (silu(h1)) -> same slot
          float hv = bf2f(outb[(size_t)m * ldc + n]);
          outb[(size_t)m * ldc + n] = f2bf(v * hv);
        }
      }
    }
  }
}

// ---------------- Flash attention (causal, GQA 4:1) ----------------
// block = 4 waves; wave w owns 16 q rows; q-tile = 64 rows; kv-tile = 64.
__global__ __launch_bounds__(256) void flash_k(const ushort* __restrict__ qkv,
                                               ushort* __restrict__ o) {
  const int qb = blockIdx.x, h = blockIdx.y;
  const int kvh = h >> 2;
  const int tid = threadIdx.x;
  const int lane = tid & 63, w = tid >> 6;
  const int g = lane >> 4, r16 = lane & 15;

  __shared__ __align__(16) ushort Ks[64 * 72];
  __shared__ __align__(16) ushort Vt[64 * 72];
  __shared__ __align__(16) ushort Pl[4 * 16 * 72];

  bf16x8 qf0, qf1;
  {
    const ushort* qp = qkv + (size_t)(qb * 64 + w * 16 + r16) * 3072 + h * HD;
    qf0 = *(const bf16x8*)(qp + g * 8);
    qf1 = *(const bf16x8*)(qp + 32 + g * 8);
  }
  f32x4 accO[4];
#pragma unroll
  for (int i = 0; i < 4; i++) accO[i] = (f32x4){0, 0, 0, 0};
  float mrow[4], lrow[4];
#pragma unroll
  for (int i = 0; i < 4; i++) {
    mrow[i] = -1e30f;
    lrow[i] = 0.f;
  }
  ushort* pw = Pl + w * 16 * 72;

  for (int jb = 0; jb <= qb; ++jb) {
    __syncthreads();
    {
      const ushort* kg = qkv + (size_t)(jb * 64) * 3072 + DMODEL + kvh * HD;
      const ushort* vg = kg + 512;
#pragma unroll
      for (int p = 0; p < 2; p++) {
        int t = (p * 4 + w) * 64 + lane;
        int r = t >> 3, c = (t & 7) << 3;
        *(bf16x8*)(Ks + r * 72 + c) = *(const bf16x8*)(kg + (size_t)r * 3072 + c);
        bf16x8 vv = *(const bf16x8*)(vg + (size_t)r * 3072 + c);
#pragma unroll
        for (int i = 0; i < 8; i++) Vt[(c + i) * 72 + r] = (ushort)vv[i];
      }
    }
    __syncthreads();

    f32x4 sarr[4];
#pragma unroll
    for (int nt = 0; nt < 4; nt++) {
      bf16x8 k0 = *(const bf16x8*)(Ks + (nt * 16 + r16) * 72 + g * 8);
      bf16x8 k1 = *(const bf16x8*)(Ks + (nt * 16 + r16) * 72 + 32 + g * 8);
      f32x4 z = (f32x4){0, 0, 0, 0};
      z = MFMA(qf0, k0, z);
      z = MFMA(qf1, k1, z);
      sarr[nt] = z;
    }
    const int q0 = qb * 64 + w * 16 + g * 4;
#pragma unroll
    for (int nt = 0; nt < 4; nt++) {
      int kvc = jb * 64 + nt * 16 + r16;
#pragma unroll
      for (int reg = 0; reg < 4; reg++) {
        float xv = sarr[nt][reg] * 0.125f;
        sarr[nt][reg] = (kvc > q0 + reg) ? -1e30f : xv;
      }
    }
    float pm[4];
#pragma unroll
    for (int reg = 0; reg < 4; reg++)
      pm[reg] = fmaxf(fmaxf(sarr[0][reg], sarr[1][reg]),
                      fmaxf(sarr[2][reg], sarr[3][reg]));
#pragma unroll
    for (int off = 1; off < 16; off <<= 1)
#pragma unroll
      for (int reg = 0; reg < 4; reg++)
        pm[reg] = fmaxf(pm[reg], __shfl_xor(pm[reg], off, 16));
    float sc[4], rs[4];
#pragma unroll
    for (int reg = 0; reg < 4; reg++) {
      float mn = fmaxf(mrow[reg], pm[reg]);
      sc[reg] = __expf(mrow[reg] - mn);
      mrow[reg] = mn;
      rs[reg] = 0.f;
    }
#pragma unroll
    for (int dt = 0; dt < 4; dt++)
#pragma unroll
      for (int reg = 0; reg < 4; reg++) accO[dt][reg] *= sc[reg];
#pragma unroll
    for (int nt = 0; nt < 4; nt++)
#pragma unroll
      for (int reg = 0; reg < 4; reg++) {
        float pv = __expf(sarr[nt][reg] - mrow[reg]);
        rs[reg] += pv;
        sarr[nt][reg] = pv;
      }
#pragma unroll
    for (int off = 1; off < 16; off <<= 1)
#pragma unroll
      for (int reg = 0; reg < 4; reg++)
        rs[reg] += __shfl_xor(rs[reg], off, 16);
#pragma unroll
    for (int reg = 0; reg < 4; reg++)
      lrow[reg] = lrow[reg] * sc[reg] + rs[reg];
#pragma unroll
    for (int nt = 0; nt < 4; nt++)
#pragma unroll
      for (int reg = 0; reg < 4; reg++)
        pw[(g * 4 + reg) * 72 + nt * 16 + r16] = f2bf(sarr[nt][reg]);
    // PV
#pragma unroll
    for (int kk = 0; kk < 2; kk++) {
      bf16x8 pa = *(const bf16x8*)(pw + r16 * 72 + kk * 32 + g * 8);
#pragma unroll
      for (int dt = 0; dt < 4; dt++) {
        bf16x8 vb = *(const bf16x8*)(Vt + (dt * 16 + r16) * 72 + kk * 32 + g * 8);
        accO[dt] = MFMA(pa, vb, accO[dt]);
      }
    }
  }
  float inv[4];
#pragma unroll
  for (int reg = 0; reg < 4; reg++) inv[reg] = 1.f / lrow[reg];
#pragma unroll
  for (int dt = 0; dt < 4; dt++)
#pragma unroll
    for (int reg = 0; reg < 4; reg++)
      o[(size_t)(qb * 64 + w * 16 + g * 4 + reg) * DMODEL + h * HD + dt * 16 +
        r16] = f2bf(accO[dt][reg] * inv[reg]);
}

extern "C" void kernel_launch(void* const* d_in, const int* in_sizes, int n_in,
                              void* d_out, int out_size, void* d_ws,
                              size_t ws_size, hipStream_t stream) {
  (void)in_sizes; (void)n_in; (void)out_size; (void)ws_size;
  const float* hidden = (const float*)d_in[0];
  const float* cosb = (const float*)d_in[1];
  const float* sinb = (const float*)d_in[2];
  const float* wq = (const float*)d_in[4];
  const float* bq = (const float*)d_in[5];
  const float* wk = (const float*)d_in[6];
  const float* bk = (const float*)d_in[7];
  const float* wv = (const float*)d_in[8];
  const float* bv = (const float*)d_in[9];
  const float* wo = (const float*)d_in[10];
  const float* bo = (const float*)d_in[11];
  const float* ln1 = (const float*)d_in[12];
  const float* ln2 = (const float*)d_in[13];
  const float* w1 = (const float*)d_in[16];
  const float* b1 = (const float*)d_in[17];
  const float* w2 = (const float*)d_in[18];
  const float* b2 = (const float*)d_in[19];
  const float* w3 = (const float*)d_in[20];
  const float* b3 = (const float*)d_in[21];
  float* out = (float*)d_out;

  char* ws = (char*)d_ws;
  ushort* x1 = (ushort*)ws;   ws += (size_t)S_LEN * DMODEL * 2;
  ushort* qkv = (ushort*)ws;  ws += (size_t)S_LEN * 3072 * 2;
  ushort* att = (ushort*)ws;  ws += (size_t)S_LEN * DMODEL * 2;
  ushort* x2 = (ushort*)ws;   ws += (size_t)S_LEN * DMODEL * 2;
  ushort* hbuf = (ushort*)ws; ws += (size_t)S_LEN * FFN_DIM * 2;

  // 1. RMSNorm -> x1 (bf16)
  rmsnorm_k<<<S_LEN, 256, 0, stream>>>(hidden, ln1, x1);
  // 2. QKV projections (q | k | v into one [S][3072] buffer)
  gemm_bt<EPI_BF16><<<dim3(16, 16), 256, 0, stream>>>(
      x1, DMODEL, wq, DMODEL, bq, nullptr, 0, qkv, nullptr, 3072, 0, DMODEL);
  gemm_bt<EPI_BF16><<<dim3(16, 4), 256, 0, stream>>>(
      x1, DMODEL, wk, DMODEL, bk, nullptr, 0, qkv, nullptr, 3072, 2048, DMODEL);
  gemm_bt<EPI_BF16><<<dim3(16, 4), 256, 0, stream>>>(
      x1, DMODEL, wv, DMODEL, bv, nullptr, 0, qkv, nullptr, 3072, 2560, DMODEL);
  // 3. RoPE on q and k
  rope_k<<<(S_LEN * (NH + NKV) * 32) / 256, 256, 0, stream>>>(qkv, cosb, sinb);
  // 4. Flash attention -> att (bf16, [S][H*HD])
  flash_k<<<dim3(S_LEN / 64, NH), 256, 0, stream>>>(qkv, att);
  // 5. O-proj + residual -> d_out (f32) == resid1
  gemm_bt<EPI_RESID><<<dim3(16, 16), 256, 0, stream>>>(
      att, DMODEL, wo, DMODEL, bo, hidden, DMODEL, nullptr, out, DMODEL, 0,
      DMODEL);
  // 6. RMSNorm2 -> x2 (bf16)
  rmsnorm_k<<<S_LEN, 256, 0, stream>>>(out, ln2, x2);
  // 7. h = silu(x2 @ w1^T + b1)
  gemm_bt<EPI_SILU><<<dim3(16, 64), 256, 0, stream>>>(
      x2, DMODEL, w1, DMODEL, b1, nullptr, 0, hbuf, nullptr, FFN_DIM, 0,
      DMODEL);
  // 8. h *= (x2 @ w3^T + b3)
  gemm_bt<EPI_MUL><<<dim3(16, 64), 256, 0, stream>>>(
      x2, DMODEL, w3, DMODEL, b3, nullptr, 0, hbuf, nullptr, FFN_DIM, 0,
      DMODEL);
  // 9. d_out = resid1 + h @ w2^T + b2
  gemm_bt<EPI_RESID><<<dim3(16, 16), 256, 0, stream>>>(
      hbuf, FFN_DIM, w2, FFN_DIM, b2, out, DMODEL, nullptr, out, DMODEL, 0,
      FFN_DIM);
}

// Round 2
// 755.650 us; speedup vs baseline: 1.6432x; 1.6432x over previous
//
#include <hip/hip_runtime.h>

#define S_LEN 2048
#define DMODEL 2048
#define NH 32
#define NKV 8
#define HD 64
#define FFN_DIM 8192

typedef __attribute__((ext_vector_type(4))) float f32x4;
typedef __attribute__((ext_vector_type(8))) short bf16x8;

#define MFMA(a, b, c) __builtin_amdgcn_mfma_f32_16x16x32_bf16(a, b, c, 0, 0, 0)

__device__ __forceinline__ ushort f2bf(float f) {
  unsigned u = __float_as_uint(f);
  unsigned r = (u + 0x7fffu + ((u >> 16) & 1u)) >> 16;
  return (ushort)r;
}
__device__ __forceinline__ float bf2f(ushort s) {
  return __uint_as_float(((unsigned)s) << 16);
}

__device__ __forceinline__ void gload16(const void* g, void* l) {
  __builtin_amdgcn_global_load_lds(
      (const __attribute__((address_space(1))) void*)g,
      (__attribute__((address_space(3))) void*)l, 16, 0, 0);
}

// ---------------- f32 -> bf16 weight conversion (8 elems/thread) ----------------
__global__ __launch_bounds__(256) void cvt_k(const float* __restrict__ in,
                                             ushort* __restrict__ out) {
  int i = blockIdx.x * 256 + threadIdx.x;
  f32x4 a = ((const f32x4*)in)[i * 2];
  f32x4 b = ((const f32x4*)in)[i * 2 + 1];
  bf16x8 r;
#pragma unroll
  for (int j = 0; j < 4; j++) r[j] = (short)f2bf(a[j]);
#pragma unroll
  for (int j = 0; j < 4; j++) r[4 + j] = (short)f2bf(b[j]);
  ((bf16x8*)out)[i] = r;
}

// concat 3 bias vectors (q:2048, k:512, v:512) -> 3072 floats
__global__ __launch_bounds__(256) void bias3_k(const float* __restrict__ a,
                                               const float* __restrict__ b,
                                               const float* __restrict__ c,
                                               float* __restrict__ out) {
  int i = blockIdx.x * 256 + threadIdx.x;
  float v;
  if (i < 2048) v = a[i];
  else if (i < 2560) v = b[i - 2048];
  else v = c[i - 2560];
  out[i] = v;
}

// ---------------- RMSNorm: f32 in -> bf16 out ----------------
__global__ __launch_bounds__(256) void rmsnorm_k(const float* __restrict__ in,
                                                 const float* __restrict__ w,
                                                 ushort* __restrict__ out) {
  const int row = blockIdx.x;
  const int tid = threadIdx.x;
  const float* x = in + (size_t)row * DMODEL;
  f32x4 v0 = *(const f32x4*)(x + tid * 8);
  f32x4 v1 = *(const f32x4*)(x + tid * 8 + 4);
  float ss = v0[0] * v0[0] + v0[1] * v0[1] + v0[2] * v0[2] + v0[3] * v0[3] +
             v1[0] * v1[0] + v1[1] * v1[1] + v1[2] * v1[2] + v1[3] * v1[3];
#pragma unroll
  for (int off = 32; off; off >>= 1) ss += __shfl_xor(ss, off, 64);
  __shared__ float red[4];
  if ((tid & 63) == 0) red[tid >> 6] = ss;
  __syncthreads();
  float tot = red[0] + red[1] + red[2] + red[3];
  float inv = rsqrtf(tot * (1.f / DMODEL) + 1e-5f);
#pragma unroll
  for (int i = 0; i < 8; i++) {
    int c = tid * 8 + i;
    float val = (i < 4) ? v0[i] : v1[i - 4];
    out[(size_t)row * DMODEL + c] = f2bf(w[c] * val * inv);
  }
}

// ---------------- RoPE (in-place on bf16 qkv buffer) ----------------
__global__ __launch_bounds__(256) void rope_k(ushort* __restrict__ qkv,
                                              const float* __restrict__ cs,
                                              const float* __restrict__ sn) {
  int idx = blockIdx.x * 256 + threadIdx.x;
  int d = idx & 31;
  int t = idx >> 5;
  int head = t % (NH + NKV);
  int s = t / (NH + NKV);
  int col = (head < NH) ? head * HD : DMODEL + (head - NH) * HD;
  ushort* p = qkv + (size_t)s * 3072 + col;
  float lo = bf2f(p[d]), hi = bf2f(p[d + 32]);
  float c = cs[s * HD + d], si = sn[s * HD + d];
  p[d] = f2bf(lo * c - hi * si);
  p[d + 32] = f2bf(hi * c + lo * si);
}

// ---------------- GEMM: C[M,N] = A(bf16)[M,K] @ B(bf16)[N,K]^T + bias ----------------
// m97 structure: 128x128 tile, 4 waves (2x2), BK=32, global_load_lds width-16
// for both tiles, 16 MFMA/wave/K-step. XCD-aware bijective block swizzle.
enum { EPI_BF16 = 0, EPI_RESID = 1, EPI_SILU = 2, EPI_MUL = 3 };

template <int EPI>
__global__ __launch_bounds__(256) void gemm_bt(
    const ushort* __restrict__ A, int lda, const ushort* __restrict__ B,
    int ldb, const float* __restrict__ bias, const float* __restrict__ resid,
    int ldr, ushort* __restrict__ outb, float* __restrict__ outf, int ldc,
    int ncol0, int K) {
  __shared__ __align__(16) ushort Asm[128 * 32];
  __shared__ __align__(16) ushort Bsm[128 * 32];
  const int tid = threadIdx.x;
  const int lane = tid & 63, wid = tid >> 6;
  const int wr = wid >> 1, wc = wid & 1;
  const int g = lane >> 4, r16 = lane & 15;

  // bijective XCD swizzle (all grids here have nwg % 8 == 0)
  int nwg = gridDim.x * gridDim.y;
  int bid = blockIdx.y * gridDim.x + blockIdx.x;
  if ((nwg & 7) == 0) bid = (bid & 7) * (nwg >> 3) + (bid >> 3);
  const int m0 = (bid % gridDim.x) * 128, n0 = (bid / gridDim.x) * 128;

  const ushort* Ag = A + (size_t)m0 * lda;
  const ushort* Bg = B + (size_t)n0 * ldb;

  f32x4 acc[4][4];
#pragma unroll
  for (int i = 0; i < 4; i++)
#pragma unroll
    for (int j = 0; j < 4; j++) acc[i][j] = (f32x4){0, 0, 0, 0};

  for (int kt = 0; kt < K; kt += 32) {
#pragma unroll
    for (int p = 0; p < 2; ++p) {  // A tile 8KB, B tile 8KB
      int t = (p * 4 + wid) * 64 + lane;
      int r = t >> 2, c = (t & 3) << 3;
      gload16(Ag + (size_t)r * lda + kt + c,
              (char*)Asm + (size_t)(p * 4 + wid) * 1024);
      gload16(Bg + (size_t)r * ldb + kt + c,
              (char*)Bsm + (size_t)(p * 4 + wid) * 1024);
    }
    __syncthreads();
    bf16x8 af[4], bfr[4];
#pragma unroll
    for (int mt = 0; mt < 4; mt++)
      af[mt] = *(const bf16x8*)(Asm + (wr * 64 + mt * 16 + r16) * 32 + g * 8);
#pragma unroll
    for (int nt = 0; nt < 4; nt++)
      bfr[nt] = *(const bf16x8*)(Bsm + (wc * 64 + nt * 16 + r16) * 32 + g * 8);
#pragma unroll
    for (int mt = 0; mt < 4; mt++)
#pragma unroll
      for (int nt = 0; nt < 4; nt++)
        acc[mt][nt] = MFMA(af[mt], bfr[nt], acc[mt][nt]);
    __syncthreads();
  }

#pragma unroll
  for (int mt = 0; mt < 4; mt++) {
#pragma unroll
    for (int nt = 0; nt < 4; nt++) {
      int n = n0 + wc * 64 + nt * 16 + r16;
      float bia = bias[n];
#pragma unroll
      for (int reg = 0; reg < 4; reg++) {
        int m = m0 + wr * 64 + mt * 16 + g * 4 + reg;
        float v = acc[mt][nt][reg] + bia;
        if constexpr (EPI == EPI_BF16) {
          outb[(size_t)m * ldc + ncol0 + n] = f2bf(v);
        } else if constexpr (EPI == EPI_RESID) {
          outf[(size_t)m * ldc + n] = v + resid[(size_t)m * ldr + n];
        } else if constexpr (EPI == EPI_SILU) {
          float sv = v / (1.f + __expf(-v));
          outb[(size_t)m * ldc + n] = f2bf(sv);
        } else {  // EPI_MUL: v * existing (silu(h1)) -> same slot
          float hv = bf2f(outb[(size_t)m * ldc + n]);
          outb[(size_t)m * ldc + n] = f2bf(v * hv);
        }
      }
    }
  }
}

// ---------------- Flash attention (causal, GQA 4:1) ----------------
__global__ __launch_bounds__(256) void flash_k(const ushort* __restrict__ qkv,
                                               ushort* __restrict__ o) {
  const int qb = blockIdx.x, h = blockIdx.y;
  const int kvh = h >> 2;
  const int tid = threadIdx.x;
  const int lane = tid & 63, w = tid >> 6;
  const int g = lane >> 4, r16 = lane & 15;

  __shared__ __align__(16) ushort Ks[64 * 72];
  __shared__ __align__(16) ushort Vt[64 * 72];
  __shared__ __align__(16) ushort Pl[4 * 16 * 72];

  bf16x8 qf0, qf1;
  {
    const ushort* qp = qkv + (size_t)(qb * 64 + w * 16 + r16) * 3072 + h * HD;
    qf0 = *(const bf16x8*)(qp + g * 8);
    qf1 = *(const bf16x8*)(qp + 32 + g * 8);
  }
  f32x4 accO[4];
#pragma unroll
  for (int i = 0; i < 4; i++) accO[i] = (f32x4){0, 0, 0, 0};
  float mrow[4], lrow[4];
#pragma unroll
  for (int i = 0; i < 4; i++) {
    mrow[i] = -1e30f;
    lrow[i] = 0.f;
  }
  ushort* pw = Pl + w * 16 * 72;

  for (int jb = 0; jb <= qb; ++jb) {
    __syncthreads();
    {
      const ushort* kg = qkv + (size_t)(jb * 64) * 3072 + DMODEL + kvh * HD;
      const ushort* vg = kg + 512;
#pragma unroll
      for (int p = 0; p < 2; p++) {
        int t = (p * 4 + w) * 64 + lane;
        int r = t >> 3, c = (t & 7) << 3;
        *(bf16x8*)(Ks + r * 72 + c) = *(const bf16x8*)(kg + (size_t)r * 3072 + c);
        bf16x8 vv = *(const bf16x8*)(vg + (size_t)r * 3072 + c);
#pragma unroll
        for (int i = 0; i < 8; i++) Vt[(c + i) * 72 + r] = (ushort)vv[i];
      }
    }
    __syncthreads();

    f32x4 sarr[4];
#pragma unroll
    for (int nt = 0; nt < 4; nt++) {
      bf16x8 k0 = *(const bf16x8*)(Ks + (nt * 16 + r16) * 72 + g * 8);
      bf16x8 k1 = *(const bf16x8*)(Ks + (nt * 16 + r16) * 72 + 32 + g * 8);
      f32x4 z = (f32x4){0, 0, 0, 0};
      z = MFMA(qf0, k0, z);
      z = MFMA(qf1, k1, z);
      sarr[nt] = z;
    }
    const int q0 = qb * 64 + w * 16 + g * 4;
#pragma unroll
    for (int nt = 0; nt < 4; nt++) {
      int kvc = jb * 64 + nt * 16 + r16;
#pragma unroll
      for (int reg = 0; reg < 4; reg++) {
        float xv = sarr[nt][reg] * 0.125f;
        sarr[nt][reg] = (kvc > q0 + reg) ? -1e30f : xv;
      }
    }
    float pm[4];
#pragma unroll
    for (int reg = 0; reg < 4; reg++)
      pm[reg] = fmaxf(fmaxf(sarr[0][reg], sarr[1][reg]),
                      fmaxf(sarr[2][reg], sarr[3][reg]));
#pragma unroll
    for (int off = 1; off < 16; off <<= 1)
#pragma unroll
      for (int reg = 0; reg < 4; reg++)
        pm[reg] = fmaxf(pm[reg], __shfl_xor(pm[reg], off, 16));
    float sc[4], rs[4];
#pragma unroll
    for (int reg = 0; reg < 4; reg++) {
      float mn = fmaxf(mrow[reg], pm[reg]);
      sc[reg] = __expf(mrow[reg] - mn);
      mrow[reg] = mn;
      rs[reg] = 0.f;
    }
#pragma unroll
    for (int dt = 0; dt < 4; dt++)
#pragma unroll
      for (int reg = 0; reg < 4; reg++) accO[dt][reg] *= sc[reg];
#pragma unroll
    for (int nt = 0; nt < 4; nt++)
#pragma unroll
      for (int reg = 0; reg < 4; reg++) {
        float pv = __expf(sarr[nt][reg] - mrow[reg]);
        rs[reg] += pv;
        sarr[nt][reg] = pv;
      }
#pragma unroll
    for (int off = 1; off < 16; off <<= 1)
#pragma unroll
      for (int reg = 0; reg < 4; reg++)
        rs[reg] += __shfl_xor(rs[reg], off, 16);
#pragma unroll
    for (int reg = 0; reg < 4; reg++)
      lrow[reg] = lrow[reg] * sc[reg] + rs[reg];
#pragma unroll
    for (int nt = 0; nt < 4; nt++)
#pragma unroll
      for (int reg = 0; reg < 4; reg++)
        pw[(g * 4 + reg) * 72 + nt * 16 + r16] = f2bf(sarr[nt][reg]);
    // PV
#pragma unroll
    for (int kk = 0; kk < 2; kk++) {
      bf16x8 pa = *(const bf16x8*)(pw + r16 * 72 + kk * 32 + g * 8);
#pragma unroll
      for (int dt = 0; dt < 4; dt++) {
        bf16x8 vb = *(const bf16x8*)(Vt + (dt * 16 + r16) * 72 + kk * 32 + g * 8);
        accO[dt] = MFMA(pa, vb, accO[dt]);
      }
    }
  }
  float inv[4];
#pragma unroll
  for (int reg = 0; reg < 4; reg++) inv[reg] = 1.f / lrow[reg];
#pragma unroll
  for (int dt = 0; dt < 4; dt++)
#pragma unroll
    for (int reg = 0; reg < 4; reg++)
      o[(size_t)(qb * 64 + w * 16 + g * 4 + reg) * DMODEL + h * HD + dt * 16 +
        r16] = f2bf(accO[dt][reg] * inv[reg]);
}

extern "C" void kernel_launch(void* const* d_in, const int* in_sizes, int n_in,
                              void* d_out, int out_size, void* d_ws,
                              size_t ws_size, hipStream_t stream) {
  (void)in_sizes; (void)n_in; (void)out_size; (void)ws_size;
  const float* hidden = (const float*)d_in[0];
  const float* cosb = (const float*)d_in[1];
  const float* sinb = (const float*)d_in[2];
  const float* wq = (const float*)d_in[4];
  const float* bq = (const float*)d_in[5];
  const float* wk = (const float*)d_in[6];
  const float* bk = (const float*)d_in[7];
  const float* wv = (const float*)d_in[8];
  const float* bv = (const float*)d_in[9];
  const float* wo = (const float*)d_in[10];
  const float* bo = (const float*)d_in[11];
  const float* ln1 = (const float*)d_in[12];
  const float* ln2 = (const float*)d_in[13];
  const float* w1 = (const float*)d_in[16];
  const float* b1 = (const float*)d_in[17];
  const float* w2 = (const float*)d_in[18];
  const float* b2 = (const float*)d_in[19];
  const float* w3 = (const float*)d_in[20];
  const float* b3 = (const float*)d_in[21];
  float* out = (float*)d_out;

  char* ws = (char*)d_ws;
  ushort* x1 = (ushort*)ws;   ws += (size_t)S_LEN * DMODEL * 2;       // 8MB
  ushort* qkv = (ushort*)ws;  ws += (size_t)S_LEN * 3072 * 2;         // 12MB
  ushort* att = (ushort*)ws;  ws += (size_t)S_LEN * DMODEL * 2;       // 8MB
  ushort* x2 = (ushort*)ws;   ws += (size_t)S_LEN * DMODEL * 2;       // 8MB
  ushort* hbuf = (ushort*)ws; ws += (size_t)S_LEN * FFN_DIM * 2;      // 32MB
  ushort* wbuf = (ushort*)ws; ws += (size_t)FFN_DIM * DMODEL * 2;     // 32MB
  float* bqkv = (float*)ws;   ws += 3072 * 4;

  // 1. RMSNorm -> x1 (bf16)
  rmsnorm_k<<<S_LEN, 256, 0, stream>>>(hidden, ln1, x1);

  // 2. Convert + concat QKV weights -> wbuf [3072][2048] bf16, biases -> bqkv
  cvt_k<<<(2048 * 2048) / 2048, 256, 0, stream>>>(wq, wbuf);
  cvt_k<<<(512 * 2048) / 2048, 256, 0, stream>>>(wk, wbuf + 2048 * 2048);
  cvt_k<<<(512 * 2048) / 2048, 256, 0, stream>>>(wv, wbuf + 2560 * 2048);
  bias3_k<<<12, 256, 0, stream>>>(bq, bk, bv, bqkv);

  // 3. Fused QKV GEMM -> qkv [S][3072]
  gemm_bt<EPI_BF16><<<dim3(16, 24), 256, 0, stream>>>(
      x1, DMODEL, wbuf, DMODEL, bqkv, nullptr, 0, qkv, nullptr, 3072, 0,
      DMODEL);

  // 4. RoPE on q and k
  rope_k<<<(S_LEN * (NH + NKV) * 32) / 256, 256, 0, stream>>>(qkv, cosb, sinb);

  // 5. Flash attention -> att
  flash_k<<<dim3(S_LEN / 64, NH), 256, 0, stream>>>(qkv, att);

  // 6. O-proj + residual -> d_out (f32)
  cvt_k<<<(2048 * 2048) / 2048, 256, 0, stream>>>(wo, wbuf);
  gemm_bt<EPI_RESID><<<dim3(16, 16), 256, 0, stream>>>(
      att, DMODEL, wbuf, DMODEL, bo, hidden, DMODEL, nullptr, out, DMODEL, 0,
      DMODEL);

  // 7. RMSNorm2 -> x2
  rmsnorm_k<<<S_LEN, 256, 0, stream>>>(out, ln2, x2);

  // 8. h = silu(x2 @ w1^T + b1)
  cvt_k<<<(FFN_DIM * 2048) / 2048, 256, 0, stream>>>(w1, wbuf);
  gemm_bt<EPI_SILU><<<dim3(16, 64), 256, 0, stream>>>(
      x2, DMODEL, wbuf, DMODEL, b1, nullptr, 0, hbuf, nullptr, FFN_DIM, 0,
      DMODEL);

  // 9. h *= (x2 @ w3^T + b3)
  cvt_k<<<(FFN_DIM * 2048) / 2048, 256, 0, stream>>>(w3, wbuf);
  gemm_bt<EPI_MUL><<<dim3(16, 64), 256, 0, stream>>>(
      x2, DMODEL, wbuf, DMODEL, b3, nullptr, 0, hbuf, nullptr, FFN_DIM, 0,
      DMODEL);

  // 10. d_out = resid1 + h @ w2^T + b2
  cvt_k<<<(DMODEL * FFN_DIM) / 2048, 256, 0, stream>>>(w2, wbuf);
  gemm_bt<EPI_RESID><<<dim3(16, 16), 256, 0, stream>>>(
      hbuf, FFN_DIM, wbuf, FFN_DIM, b2, out, DMODEL, nullptr, out, DMODEL, 0,
      FFN_DIM);
}

// Round 3
// 586.784 us; speedup vs baseline: 2.1161x; 1.2878x over previous
//
#include <hip/hip_runtime.h>

#define S_LEN 2048
#define DMODEL 2048
#define NH 32
#define NKV 8
#define HD 64
#define FFN_DIM 8192

typedef __attribute__((ext_vector_type(4))) float f32x4;
typedef __attribute__((ext_vector_type(8))) short bf16x8;

#define MFMA(a, b, c) __builtin_amdgcn_mfma_f32_16x16x32_bf16(a, b, c, 0, 0, 0)

__device__ __forceinline__ ushort f2bf(float f) {
  unsigned u = __float_as_uint(f);
  unsigned r = (u + 0x7fffu + ((u >> 16) & 1u)) >> 16;
  return (ushort)r;
}
__device__ __forceinline__ float bf2f(ushort s) {
  return __uint_as_float(((unsigned)s) << 16);
}

__device__ __forceinline__ void gload16(const void* g, void* l) {
  __builtin_amdgcn_global_load_lds(
      (const __attribute__((address_space(1))) void*)g,
      (__attribute__((address_space(3))) void*)l, 16, 0, 0);
}

__device__ __forceinline__ void phase_bar() {
  asm volatile("" ::: "memory");
  __builtin_amdgcn_sched_barrier(0);
  __builtin_amdgcn_s_barrier();
  __builtin_amdgcn_sched_barrier(0);
  asm volatile("" ::: "memory");
}

// ---------------- f32 -> bf16 conversion ----------------
__global__ __launch_bounds__(256) void cvt_k(const float* __restrict__ in,
                                             ushort* __restrict__ out) {
  int i = blockIdx.x * 256 + threadIdx.x;
  f32x4 a = ((const f32x4*)in)[i * 2];
  f32x4 b = ((const f32x4*)in)[i * 2 + 1];
  bf16x8 r;
#pragma unroll
  for (int j = 0; j < 4; j++) r[j] = (short)f2bf(a[j]);
#pragma unroll
  for (int j = 0; j < 4; j++) r[4 + j] = (short)f2bf(b[j]);
  ((bf16x8*)out)[i] = r;
}

__global__ __launch_bounds__(256) void bias3_k(const float* __restrict__ a,
                                               const float* __restrict__ b,
                                               const float* __restrict__ c,
                                               float* __restrict__ out) {
  int i = blockIdx.x * 256 + threadIdx.x;
  float v;
  if (i < 2048) v = a[i];
  else if (i < 2560) v = b[i - 2048];
  else v = c[i - 2560];
  out[i] = v;
}

// ---------------- RMSNorm ----------------
__global__ __launch_bounds__(256) void rmsnorm_k(const float* __restrict__ in,
                                                 const float* __restrict__ w,
                                                 ushort* __restrict__ out) {
  const int row = blockIdx.x;
  const int tid = threadIdx.x;
  const float* x = in + (size_t)row * DMODEL;
  f32x4 v0 = *(const f32x4*)(x + tid * 8);
  f32x4 v1 = *(const f32x4*)(x + tid * 8 + 4);
  float ss = v0[0] * v0[0] + v0[1] * v0[1] + v0[2] * v0[2] + v0[3] * v0[3] +
             v1[0] * v1[0] + v1[1] * v1[1] + v1[2] * v1[2] + v1[3] * v1[3];
#pragma unroll
  for (int off = 32; off; off >>= 1) ss += __shfl_xor(ss, off, 64);
  __shared__ float red[4];
  if ((tid & 63) == 0) red[tid >> 6] = ss;
  __syncthreads();
  float tot = red[0] + red[1] + red[2] + red[3];
  float inv = rsqrtf(tot * (1.f / DMODEL) + 1e-5f);
#pragma unroll
  for (int i = 0; i < 8; i++) {
    int c = tid * 8 + i;
    float val = (i < 4) ? v0[i] : v1[i - 4];
    out[(size_t)row * DMODEL + c] = f2bf(w[c] * val * inv);
  }
}

// ---------------- RoPE ----------------
__global__ __launch_bounds__(256) void rope_k(ushort* __restrict__ qkv,
                                              const float* __restrict__ cs,
                                              const float* __restrict__ sn) {
  int idx = blockIdx.x * 256 + threadIdx.x;
  int d = idx & 31;
  int t = idx >> 5;
  int head = t % (NH + NKV);
  int s = t / (NH + NKV);
  int col = (head < NH) ? head * HD : DMODEL + (head - NH) * HD;
  ushort* p = qkv + (size_t)s * 3072 + col;
  float lo = bf2f(p[d]), hi = bf2f(p[d + 32]);
  float c = cs[s * HD + d], si = sn[s * HD + d];
  p[d] = f2bf(lo * c - hi * si);
  p[d + 32] = f2bf(hi * c + lo * si);
}

// ======== 256x256 8-phase GEMM: C[M,N] = A[M,K] @ B[N,K]^T (+ epilogue) ========
enum { EPI_BF16 = 0, EPI_RESID = 1, EPI_SILU = 2, EPI_MUL = 3, EPI_PART = 4 };

__device__ __forceinline__ void quad(const bf16x8* Arr, const bf16x8* BR,
                                     f32x4 (*accr)[4], int qn) {
#pragma unroll
  for (int i = 0; i < 4; i++)
#pragma unroll
    for (int j = 0; j < 2; j++)
#pragma unroll
      for (int ks = 0; ks < 2; ks++)
        accr[i][qn * 2 + j] =
            MFMA(Arr[2 * i + ks], BR[2 * j + ks], accr[i][qn * 2 + j]);
}

template <int EPI>
__global__ __launch_bounds__(512, 2) void gemm256(
    const ushort* __restrict__ A, int lda, const ushort* __restrict__ B,
    int ldb, const float* __restrict__ bias, const float* __restrict__ resid,
    ushort* __restrict__ outb, float* __restrict__ outf, int ldc, int K,
    int kspan, long long opart) {
  __shared__ __align__(16) ushort lds[65536];  // 128KB: 2 buf x 4 slots x 8192
  const int tid = threadIdx.x;
  const int l = tid & 63, w = tid >> 6;
  const int g = l >> 4, r16 = l & 15;
  const int wm = w >> 2, wn = w & 3;

  int nwg = gridDim.x * gridDim.y;
  int bid = blockIdx.y * gridDim.x + blockIdx.x;
  bid = (bid & 7) * (nwg >> 3) + (bid >> 3);  // XCD swizzle (nwg%8==0)
  const int m0 = (bid % gridDim.x) * 256;
  const int n0 = (bid / gridDim.x) * 256;
  const int z = blockIdx.z;

  const ushort* Ag = A + (size_t)z * kspan + (size_t)m0 * lda;
  const ushort* Bg = B + (size_t)z * kspan + (size_t)n0 * ldb;
  ushort* outbz = outb;
  if (EPI == EPI_PART) outbz = outb + (size_t)z * opart;

  const int NT = K >> 6;

  // staging lane geometry (inverse-swizzled global source, linear LDS dest)
  const int stgRow = w * 8 + (l >> 3);
  const int stgCol = ((l & 7) ^ (l >> 3)) * 8;

  // read pointers (swizzled): frag row R -> byte col ^= (R&7)<<4, R&7 == r16&7
  const int xa = (r16 & 7) << 4;
  const int c0 = ((g * 16) ^ xa) >> 1;
  const int c1 = c0 ^ 32;
  const int slotA = wm ? 3 : 1;
  const int slotB = (wn >> 1) ? 2 : 0;
  const ushort* pA0 = lds + slotA * 8192 + r16 * 64 + c0;
  const ushort* pA1 = lds + slotA * 8192 + r16 * 64 + c1;
  const ushort* pB0 = lds + slotB * 8192 + ((wn & 1) * 64 + r16) * 64 + c0;
  const ushort* pB1 = lds + slotB * 8192 + ((wn & 1) * 64 + r16) * 64 + c1;

  f32x4 acc[8][4];
#pragma unroll
  for (int i = 0; i < 8; i++)
#pragma unroll
    for (int j = 0; j < 4; j++) acc[i][j] = (f32x4){0, 0, 0, 0};

  auto stageA = [&](int slot, int tile, int hf) {
    ushort* dst = lds + ((tile & 1) * 32768 + slot * 8192 + w * 512);
    const ushort* src =
        Ag + (size_t)(hf * 128 + stgRow) * lda + tile * 64 + stgCol;
    gload16(src, dst);
    gload16(src + (size_t)64 * lda, dst + 4096);
  };
  auto stageB = [&](int slot, int tile, int hf) {
    ushort* dst = lds + ((tile & 1) * 32768 + slot * 8192 + w * 512);
    const ushort* src =
        Bg + (size_t)(hf * 128 + stgRow) * ldb + tile * 64 + stgCol;
    gload16(src, dst);
    gload16(src + (size_t)64 * ldb, dst + 4096);
  };

  // prologue: tile0 all 4 halves + tile1 B0,A0 (12 loads), complete tile0
  stageB(0, 0, 0);
  stageA(1, 0, 0);
  stageB(2, 0, 1);
  stageA(3, 0, 1);
  stageB(0, 1, 0);
  stageA(1, 1, 0);
  asm volatile("s_waitcnt vmcnt(4)" ::: "memory");
  phase_bar();

  bf16x8 Ar[8], Br0[4], Br1[4];

  for (int t = 0; t < NT; ++t) {
    const int bo = (t & 1) * 32768;
    // ---- q0: read A(mf0-3), B(nf0-1); stage B1(t+1); MFMA quad(0,0)
#pragma unroll
    for (int i = 0; i < 4; i++) {
      Ar[2 * i] = *(const bf16x8*)(pA0 + bo + i * 1024);
      Ar[2 * i + 1] = *(const bf16x8*)(pA1 + bo + i * 1024);
    }
#pragma unroll
    for (int j = 0; j < 2; j++) {
      Br0[2 * j] = *(const bf16x8*)(pB0 + bo + j * 1024);
      Br0[2 * j + 1] = *(const bf16x8*)(pB1 + bo + j * 1024);
    }
    if (t + 1 < NT) stageB(2, t + 1, 1);
    phase_bar();
    __builtin_amdgcn_s_setprio(1);
    quad(Ar, Br0, &acc[0], 0);
    __builtin_amdgcn_s_setprio(0);
    phase_bar();
    // ---- q1: read B(nf2-3); stage A1(t+1); MFMA quad(0,1)
#pragma unroll
    for (int j = 0; j < 2; j++) {
      Br1[2 * j] = *(const bf16x8*)(pB0 + bo + (j + 2) * 1024);
      Br1[2 * j + 1] = *(const bf16x8*)(pB1 + bo + (j + 2) * 1024);
    }
    if (t + 1 < NT) stageA(3, t + 1, 1);
    phase_bar();
    __builtin_amdgcn_s_setprio(1);
    quad(Ar, Br1, &acc[0], 1);
    __builtin_amdgcn_s_setprio(0);
    phase_bar();
    // ---- q2: read A(mf4-7); stage B0(t+2); MFMA quad(1,1)
#pragma unroll
    for (int i = 0; i < 4; i++) {
      Ar[2 * i] = *(const bf16x8*)(pA0 + bo + (i + 4) * 1024);
      Ar[2 * i + 1] = *(const bf16x8*)(pA1 + bo + (i + 4) * 1024);
    }
    if (t + 2 < NT) stageB(0, t + 2, 0);
    phase_bar();
    __builtin_amdgcn_s_setprio(1);
    quad(Ar, Br1, &acc[4], 1);
    __builtin_amdgcn_s_setprio(0);
    phase_bar();
    // ---- q3: stage A0(t+2); MFMA quad(1,0); counted vmcnt
    if (t + 2 < NT) stageA(1, t + 2, 0);
    phase_bar();
    __builtin_amdgcn_s_setprio(1);
    quad(Ar, Br0, &acc[4], 0);
    __builtin_amdgcn_s_setprio(0);
    if (t + 2 < NT) {
      asm volatile("s_waitcnt vmcnt(4)" ::: "memory");
    } else {
      asm volatile("s_waitcnt vmcnt(0)" ::: "memory");
    }
    phase_bar();
  }

  // epilogue
#pragma unroll
  for (int mf = 0; mf < 8; mf++) {
#pragma unroll
    for (int nf = 0; nf < 4; nf++) {
      const int n = n0 + wn * 64 + nf * 16 + r16;
      float bia = (EPI == EPI_PART) ? 0.f : bias[n];
#pragma unroll
      for (int reg = 0; reg < 4; reg++) {
        const int m = m0 + wm * 128 + mf * 16 + g * 4 + reg;
        float v = acc[mf][nf][reg] + bia;
        if constexpr (EPI == EPI_BF16) {
          outbz[(size_t)m * ldc + n] = f2bf(v);
        } else if constexpr (EPI == EPI_RESID) {
          outf[(size_t)m * ldc + n] = v + resid[(size_t)m * ldc + n];
        } else if constexpr (EPI == EPI_SILU) {
          float sv = v / (1.f + __expf(-v));
          outbz[(size_t)m * ldc + n] = f2bf(sv);
        } else if constexpr (EPI == EPI_MUL) {
          float hv = bf2f(outbz[(size_t)m * ldc + n]);
          outbz[(size_t)m * ldc + n] = f2bf(v * hv);
        } else {  // EPI_PART
          outbz[(size_t)m * ldc + n] = f2bf(v);
        }
      }
    }
  }
}

// ---------------- split-K reduce for w2 ----------------
__global__ __launch_bounds__(256) void reduce_k(const ushort* __restrict__ part,
                                                const float* __restrict__ b2,
                                                float* __restrict__ out) {
  int i = (blockIdx.x * 256 + threadIdx.x) * 8;
  int col = i & (DMODEL - 1);
  float s[8];
#pragma unroll
  for (int j = 0; j < 8; j++) s[j] = out[i + j] + b2[col + j];
#pragma unroll
  for (int z = 0; z < 4; z++) {
    bf16x8 v = *(const bf16x8*)(part + (size_t)z * 4194304 + i);
#pragma unroll
    for (int j = 0; j < 8; j++) s[j] += bf2f((ushort)v[j]);
  }
#pragma unroll
  for (int j = 0; j < 8; j++) out[i + j] = s[j];
}

// ---------------- Flash attention (causal, GQA 4:1) ----------------
__global__ __launch_bounds__(256) void flash_k(const ushort* __restrict__ qkv,
                                               ushort* __restrict__ o) {
  const int qb = blockIdx.x, h = blockIdx.y;
  const int kvh = h >> 2;
  const int tid = threadIdx.x;
  const int lane = tid & 63, w = tid >> 6;
  const int g = lane >> 4, r16 = lane & 15;

  __shared__ __align__(16) ushort Ks[64 * 72];
  __shared__ __align__(16) ushort Vt[64 * 72];
  __shared__ __align__(16) ushort Pl[4 * 16 * 72];

  bf16x8 qf0, qf1;
  {
    const ushort* qp = qkv + (size_t)(qb * 64 + w * 16 + r16) * 3072 + h * HD;
    qf0 = *(const bf16x8*)(qp + g * 8);
    qf1 = *(const bf16x8*)(qp + 32 + g * 8);
  }
  f32x4 accO[4];
#pragma unroll
  for (int i = 0; i < 4; i++) accO[i] = (f32x4){0, 0, 0, 0};
  float mrow[4], lrow[4];
#pragma unroll
  for (int i = 0; i < 4; i++) {
    mrow[i] = -1e30f;
    lrow[i] = 0.f;
  }
  ushort* pw = Pl + w * 16 * 72;

  for (int jb = 0; jb <= qb; ++jb) {
    __syncthreads();
    {
      const ushort* kg = qkv + (size_t)(jb * 64) * 3072 + DMODEL + kvh * HD;
      const ushort* vg = kg + 512;
#pragma unroll
      for (int p = 0; p < 2; p++) {
        int t = (p * 4 + w) * 64 + lane;
        int r = t >> 3, c = (t & 7) << 3;
        *(bf16x8*)(Ks + r * 72 + c) = *(const bf16x8*)(kg + (size_t)r * 3072 + c);
        bf16x8 vv = *(const bf16x8*)(vg + (size_t)r * 3072 + c);
#pragma unroll
        for (int i = 0; i < 8; i++) Vt[(c + i) * 72 + r] = (ushort)vv[i];
      }
    }
    __syncthreads();

    f32x4 sarr[4];
#pragma unroll
    for (int nt = 0; nt < 4; nt++) {
      bf16x8 k0 = *(const bf16x8*)(Ks + (nt * 16 + r16) * 72 + g * 8);
      bf16x8 k1 = *(const bf16x8*)(Ks + (nt * 16 + r16) * 72 + 32 + g * 8);
      f32x4 z = (f32x4){0, 0, 0, 0};
      z = MFMA(qf0, k0, z);
      z = MFMA(qf1, k1, z);
      sarr[nt] = z;
    }
    const int q0 = qb * 64 + w * 16 + g * 4;
#pragma unroll
    for (int nt = 0; nt < 4; nt++) {
      int kvc = jb * 64 + nt * 16 + r16;
#pragma unroll
      for (int reg = 0; reg < 4; reg++) {
        float xv = sarr[nt][reg] * 0.125f;
        sarr[nt][reg] = (kvc > q0 + reg) ? -1e30f : xv;
      }
    }
    float pm[4];
#pragma unroll
    for (int reg = 0; reg < 4; reg++)
      pm[reg] = fmaxf(fmaxf(sarr[0][reg], sarr[1][reg]),
                      fmaxf(sarr[2][reg], sarr[3][reg]));
#pragma unroll
    for (int off = 1; off < 16; off <<= 1)
#pragma unroll
      for (int reg = 0; reg < 4; reg++)
        pm[reg] = fmaxf(pm[reg], __shfl_xor(pm[reg], off, 16));
    float sc[4], rs[4];
#pragma unroll
    for (int reg = 0; reg < 4; reg++) {
      float mn = fmaxf(mrow[reg], pm[reg]);
      sc[reg] = __expf(mrow[reg] - mn);
      mrow[reg] = mn;
      rs[reg] = 0.f;
    }
#pragma unroll
    for (int dt = 0; dt < 4; dt++)
#pragma unroll
      for (int reg = 0; reg < 4; reg++) accO[dt][reg] *= sc[reg];
#pragma unroll
    for (int nt = 0; nt < 4; nt++)
#pragma unroll
      for (int reg = 0; reg < 4; reg++) {
        float pv = __expf(sarr[nt][reg] - mrow[reg]);
        rs[reg] += pv;
        sarr[nt][reg] = pv;
      }
#pragma unroll
    for (int off = 1; off < 16; off <<= 1)
#pragma unroll
      for (int reg = 0; reg < 4; reg++)
        rs[reg] += __shfl_xor(rs[reg], off, 16);
#pragma unroll
    for (int reg = 0; reg < 4; reg++)
      lrow[reg] = lrow[reg] * sc[reg] + rs[reg];
#pragma unroll
    for (int nt = 0; nt < 4; nt++)
#pragma unroll
      for (int reg = 0; reg < 4; reg++)
        pw[(g * 4 + reg) * 72 + nt * 16 + r16] = f2bf(sarr[nt][reg]);
    // PV
#pragma unroll
    for (int kk = 0; kk < 2; kk++) {
      bf16x8 pa = *(const bf16x8*)(pw + r16 * 72 + kk * 32 + g * 8);
#pragma unroll
      for (int dt = 0; dt < 4; dt++) {
        bf16x8 vb = *(const bf16x8*)(Vt + (dt * 16 + r16) * 72 + kk * 32 + g * 8);
        accO[dt] = MFMA(pa, vb, accO[dt]);
      }
    }
  }
  float inv[4];
#pragma unroll
  for (int reg = 0; reg < 4; reg++) inv[reg] = 1.f / lrow[reg];
#pragma unroll
  for (int dt = 0; dt < 4; dt++)
#pragma unroll
    for (int reg = 0; reg < 4; reg++)
      o[(size_t)(qb * 64 + w * 16 + g * 4 + reg) * DMODEL + h * HD + dt * 16 +
        r16] = f2bf(accO[dt][reg] * inv[reg]);
}

extern "C" void kernel_launch(void* const* d_in, const int* in_sizes, int n_in,
                              void* d_out, int out_size, void* d_ws,
                              size_t ws_size, hipStream_t stream) {
  (void)in_sizes; (void)n_in; (void)out_size; (void)ws_size;
  const float* hidden = (const float*)d_in[0];
  const float* cosb = (const float*)d_in[1];
  const float* sinb = (const float*)d_in[2];
  const float* wq = (const float*)d_in[4];
  const float* bq = (const float*)d_in[5];
  const float* wk = (const float*)d_in[6];
  const float* bk = (const float*)d_in[7];
  const float* wv = (const float*)d_in[8];
  const float* bv = (const float*)d_in[9];
  const float* wo = (const float*)d_in[10];
  const float* bo = (const float*)d_in[11];
  const float* ln1 = (const float*)d_in[12];
  const float* ln2 = (const float*)d_in[13];
  const float* w1 = (const float*)d_in[16];
  const float* b1 = (const float*)d_in[17];
  const float* w2 = (const float*)d_in[18];
  const float* b2 = (const float*)d_in[19];
  const float* w3 = (const float*)d_in[20];
  const float* b3 = (const float*)d_in[21];
  float* out = (float*)d_out;

  char* ws = (char*)d_ws;
  ushort* part = (ushort*)ws;  // 32MB overlay on x1/qkv/att/x2 (all dead by w2)
  ushort* x1 = (ushort*)ws;   ws += (size_t)S_LEN * DMODEL * 2;   // 8MB
  ushort* qkv = (ushort*)ws;  ws += (size_t)S_LEN * 3072 * 2;     // 12MB
  ushort* att = (ushort*)ws;  ws += (size_t)S_LEN * DMODEL * 2;   // 8MB
  ushort* x2 = (ushort*)ws;   ws += (size_t)S_LEN * DMODEL * 2;   // 8MB
  ushort* hbuf = (ushort*)ws; ws += (size_t)S_LEN * FFN_DIM * 2;  // 32MB
  ushort* wbuf = (ushort*)ws; ws += (size_t)FFN_DIM * DMODEL * 2; // 32MB
  float* bqkv = (float*)ws;   ws += 3072 * 4;

  // 1. RMSNorm -> x1
  rmsnorm_k<<<S_LEN, 256, 0, stream>>>(hidden, ln1, x1);

  // 2. Convert + concat QKV weights
  cvt_k<<<(2048 * 2048) / 2048, 256, 0, stream>>>(wq, wbuf);
  cvt_k<<<(512 * 2048) / 2048, 256, 0, stream>>>(wk, wbuf + 2048 * 2048);
  cvt_k<<<(512 * 2048) / 2048, 256, 0, stream>>>(wv, wbuf + 2560 * 2048);
  bias3_k<<<12, 256, 0, stream>>>(bq, bk, bv, bqkv);

  // 3. Fused QKV GEMM -> qkv [S][3072]
  gemm256<EPI_BF16><<<dim3(8, 12), 512, 0, stream>>>(
      x1, DMODEL, wbuf, DMODEL, bqkv, nullptr, qkv, nullptr, 3072, DMODEL, 0,
      0);

  // 4. RoPE
  rope_k<<<(S_LEN * (NH + NKV) * 32) / 256, 256, 0, stream>>>(qkv, cosb, sinb);

  // 5. Flash attention -> att
  flash_k<<<dim3(S_LEN / 64, NH), 256, 0, stream>>>(qkv, att);

  // 6. O-proj + residual -> d_out (f32)
  cvt_k<<<(2048 * 2048) / 2048, 256, 0, stream>>>(wo, wbuf);
  gemm256<EPI_RESID><<<dim3(8, 8), 512, 0, stream>>>(
      att, DMODEL, wbuf, DMODEL, bo, hidden, nullptr, out, DMODEL, DMODEL, 0,
      0);

  // 7. RMSNorm2 -> x2
  rmsnorm_k<<<S_LEN, 256, 0, stream>>>(out, ln2, x2);

  // 8. h = silu(x2 @ w1^T + b1)
  cvt_k<<<(FFN_DIM * 2048) / 2048, 256, 0, stream>>>(w1, wbuf);
  gemm256<EPI_SILU><<<dim3(8, 32), 512, 0, stream>>>(
      x2, DMODEL, wbuf, DMODEL, b1, nullptr, hbuf, nullptr, FFN_DIM, DMODEL, 0,
      0);

  // 9. h *= (x2 @ w3^T + b3)
  cvt_k<<<(FFN_DIM * 2048) / 2048, 256, 0, stream>>>(w3, wbuf);
  gemm256<EPI_MUL><<<dim3(8, 32), 512, 0, stream>>>(
      x2, DMODEL, wbuf, DMODEL, b3, nullptr, hbuf, nullptr, FFN_DIM, DMODEL, 0,
      0);

  // 10. w2 split-K=4: partials (bf16) -> reduce
  cvt_k<<<(DMODEL * FFN_DIM) / 2048, 256, 0, stream>>>(w2, wbuf);
  gemm256<EPI_PART><<<dim3(8, 8, 4), 512, 0, stream>>>(
      hbuf, FFN_DIM, wbuf, FFN_DIM, nullptr, nullptr, part, nullptr, DMODEL,
      DMODEL, DMODEL, (long long)S_LEN * DMODEL);
  reduce_k<<<(S_LEN * DMODEL) / 2048, 256, 0, stream>>>(part, b2, out);
}

// Round 4
// 462.254 us; speedup vs baseline: 2.6861x; 1.2694x over previous
//
#include <hip/hip_runtime.h>

#define S_LEN 2048
#define DMODEL 2048
#define NH 32
#define NKV 8
#define HD 64
#define FFN_DIM 8192

typedef __attribute__((ext_vector_type(4))) float f32x4;
typedef __attribute__((ext_vector_type(16))) float f32x16;
typedef __attribute__((ext_vector_type(8))) short bf16x8;

#define MFMA(a, b, c) __builtin_amdgcn_mfma_f32_16x16x32_bf16(a, b, c, 0, 0, 0)
#define MFMA32(a, b, c) __builtin_amdgcn_mfma_f32_32x32x16_bf16(a, b, c, 0, 0, 0)

__device__ __forceinline__ ushort f2bf(float f) {
  unsigned u = __float_as_uint(f);
  unsigned r = (u + 0x7fffu + ((u >> 16) & 1u)) >> 16;
  return (ushort)r;
}
__device__ __forceinline__ float bf2f(ushort s) {
  return __uint_as_float(((unsigned)s) << 16);
}
__device__ __forceinline__ unsigned cvtpk(float a, float b) {
  unsigned r;
  asm("v_cvt_pk_bf16_f32 %0, %1, %2" : "=v"(r) : "v"(a), "v"(b));
  return r;
}

__device__ __forceinline__ void gload16(const void* g, void* l) {
  __builtin_amdgcn_global_load_lds(
      (const __attribute__((address_space(1))) void*)g,
      (__attribute__((address_space(3))) void*)l, 16, 0, 0);
}

__device__ __forceinline__ void phase_bar() {
  asm volatile("" ::: "memory");
  __builtin_amdgcn_sched_barrier(0);
  __builtin_amdgcn_s_barrier();
  __builtin_amdgcn_sched_barrier(0);
  asm volatile("" ::: "memory");
}

// ---------------- f32 -> bf16 conversion ----------------
__global__ __launch_bounds__(256) void cvt_k(const float* __restrict__ in,
                                             ushort* __restrict__ out) {
  int i = blockIdx.x * 256 + threadIdx.x;
  f32x4 a = ((const f32x4*)in)[i * 2];
  f32x4 b = ((const f32x4*)in)[i * 2 + 1];
  bf16x8 r;
#pragma unroll
  for (int j = 0; j < 4; j++) r[j] = (short)f2bf(a[j]);
#pragma unroll
  for (int j = 0; j < 4; j++) r[4 + j] = (short)f2bf(b[j]);
  ((bf16x8*)out)[i] = r;
}

__global__ __launch_bounds__(256) void bias3_k(const float* __restrict__ a,
                                               const float* __restrict__ b,
                                               const float* __restrict__ c,
                                               float* __restrict__ out) {
  int i = blockIdx.x * 256 + threadIdx.x;
  float v;
  if (i < 2048) v = a[i];
  else if (i < 2560) v = b[i - 2048];
  else v = c[i - 2560];
  out[i] = v;
}

// ---------------- RMSNorm ----------------
__global__ __launch_bounds__(256) void rmsnorm_k(const float* __restrict__ in,
                                                 const float* __restrict__ w,
                                                 ushort* __restrict__ out) {
  const int row = blockIdx.x;
  const int tid = threadIdx.x;
  const float* x = in + (size_t)row * DMODEL;
  f32x4 v0 = *(const f32x4*)(x + tid * 8);
  f32x4 v1 = *(const f32x4*)(x + tid * 8 + 4);
  float ss = v0[0] * v0[0] + v0[1] * v0[1] + v0[2] * v0[2] + v0[3] * v0[3] +
             v1[0] * v1[0] + v1[1] * v1[1] + v1[2] * v1[2] + v1[3] * v1[3];
#pragma unroll
  for (int off = 32; off; off >>= 1) ss += __shfl_xor(ss, off, 64);
  __shared__ float red[4];
  if ((tid & 63) == 0) red[tid >> 6] = ss;
  __syncthreads();
  float tot = red[0] + red[1] + red[2] + red[3];
  float inv = rsqrtf(tot * (1.f / DMODEL) + 1e-5f);
#pragma unroll
  for (int i = 0; i < 8; i++) {
    int c = tid * 8 + i;
    float val = (i < 4) ? v0[i] : v1[i - 4];
    out[(size_t)row * DMODEL + c] = f2bf(w[c] * val * inv);
  }
}

// ---------------- RoPE ----------------
__global__ __launch_bounds__(256) void rope_k(ushort* __restrict__ qkv,
                                              const float* __restrict__ cs,
                                              const float* __restrict__ sn) {
  int idx = blockIdx.x * 256 + threadIdx.x;
  int d = idx & 31;
  int t = idx >> 5;
  int head = t % (NH + NKV);
  int s = t / (NH + NKV);
  int col = (head < NH) ? head * HD : DMODEL + (head - NH) * HD;
  ushort* p = qkv + (size_t)s * 3072 + col;
  float lo = bf2f(p[d]), hi = bf2f(p[d + 32]);
  float c = cs[s * HD + d], si = sn[s * HD + d];
  p[d] = f2bf(lo * c - hi * si);
  p[d + 32] = f2bf(hi * c + lo * si);
}

// ======== 256x256 8-phase GEMM (unchanged from R3) ========
enum { EPI_BF16 = 0, EPI_RESID = 1, EPI_SILU = 2, EPI_MUL = 3, EPI_PART = 4 };

__device__ __forceinline__ void quad(const bf16x8* Arr, const bf16x8* BR,
                                     f32x4 (*accr)[4], int qn) {
#pragma unroll
  for (int i = 0; i < 4; i++)
#pragma unroll
    for (int j = 0; j < 2; j++)
#pragma unroll
      for (int ks = 0; ks < 2; ks++)
        accr[i][qn * 2 + j] =
            MFMA(Arr[2 * i + ks], BR[2 * j + ks], accr[i][qn * 2 + j]);
}

template <int EPI>
__global__ __launch_bounds__(512, 2) void gemm256(
    const ushort* __restrict__ A, int lda, const ushort* __restrict__ B,
    int ldb, const float* __restrict__ bias, const float* __restrict__ resid,
    ushort* __restrict__ outb, float* __restrict__ outf, int ldc, int K,
    int kspan, long long opart) {
  __shared__ __align__(16) ushort lds[65536];
  const int tid = threadIdx.x;
  const int l = tid & 63, w = tid >> 6;
  const int g = l >> 4, r16 = l & 15;
  const int wm = w >> 2, wn = w & 3;

  int nwg = gridDim.x * gridDim.y;
  int bid = blockIdx.y * gridDim.x + blockIdx.x;
  bid = (bid & 7) * (nwg >> 3) + (bid >> 3);
  const int m0 = (bid % gridDim.x) * 256;
  const int n0 = (bid / gridDim.x) * 256;
  const int z = blockIdx.z;

  const ushort* Ag = A + (size_t)z * kspan + (size_t)m0 * lda;
  const ushort* Bg = B + (size_t)z * kspan + (size_t)n0 * ldb;
  ushort* outbz = outb;
  if (EPI == EPI_PART) outbz = outb + (size_t)z * opart;

  const int NT = K >> 6;

  const int stgRow = w * 8 + (l >> 3);
  const int stgCol = ((l & 7) ^ (l >> 3)) * 8;

  const int xa = (r16 & 7) << 4;
  const int c0 = ((g * 16) ^ xa) >> 1;
  const int c1 = c0 ^ 32;
  const int slotA = wm ? 3 : 1;
  const int slotB = (wn >> 1) ? 2 : 0;
  const ushort* pA0 = lds + slotA * 8192 + r16 * 64 + c0;
  const ushort* pA1 = lds + slotA * 8192 + r16 * 64 + c1;
  const ushort* pB0 = lds + slotB * 8192 + ((wn & 1) * 64 + r16) * 64 + c0;
  const ushort* pB1 = lds + slotB * 8192 + ((wn & 1) * 64 + r16) * 64 + c1;

  f32x4 acc[8][4];
#pragma unroll
  for (int i = 0; i < 8; i++)
#pragma unroll
    for (int j = 0; j < 4; j++) acc[i][j] = (f32x4){0, 0, 0, 0};

  auto stageA = [&](int slot, int tile, int hf) {
    ushort* dst = lds + ((tile & 1) * 32768 + slot * 8192 + w * 512);
    const ushort* src =
        Ag + (size_t)(hf * 128 + stgRow) * lda + tile * 64 + stgCol;
    gload16(src, dst);
    gload16(src + (size_t)64 * lda, dst + 4096);
  };
  auto stageB = [&](int slot, int tile, int hf) {
    ushort* dst = lds + ((tile & 1) * 32768 + slot * 8192 + w * 512);
    const ushort* src =
        Bg + (size_t)(hf * 128 + stgRow) * ldb + tile * 64 + stgCol;
    gload16(src, dst);
    gload16(src + (size_t)64 * ldb, dst + 4096);
  };

  stageB(0, 0, 0);
  stageA(1, 0, 0);
  stageB(2, 0, 1);
  stageA(3, 0, 1);
  stageB(0, 1, 0);
  stageA(1, 1, 0);
  asm volatile("s_waitcnt vmcnt(4)" ::: "memory");
  phase_bar();

  bf16x8 Ar[8], Br0[4], Br1[4];

  for (int t = 0; t < NT; ++t) {
    const int bo = (t & 1) * 32768;
#pragma unroll
    for (int i = 0; i < 4; i++) {
      Ar[2 * i] = *(const bf16x8*)(pA0 + bo + i * 1024);
      Ar[2 * i + 1] = *(const bf16x8*)(pA1 + bo + i * 1024);
    }
#pragma unroll
    for (int j = 0; j < 2; j++) {
      Br0[2 * j] = *(const bf16x8*)(pB0 + bo + j * 1024);
      Br0[2 * j + 1] = *(const bf16x8*)(pB1 + bo + j * 1024);
    }
    if (t + 1 < NT) stageB(2, t + 1, 1);
    phase_bar();
    __builtin_amdgcn_s_setprio(1);
    quad(Ar, Br0, &acc[0], 0);
    __builtin_amdgcn_s_setprio(0);
    phase_bar();
#pragma unroll
    for (int j = 0; j < 2; j++) {
      Br1[2 * j] = *(const bf16x8*)(pB0 + bo + (j + 2) * 1024);
      Br1[2 * j + 1] = *(const bf16x8*)(pB1 + bo + (j + 2) * 1024);
    }
    if (t + 1 < NT) stageA(3, t + 1, 1);
    phase_bar();
    __builtin_amdgcn_s_setprio(1);
    quad(Ar, Br1, &acc[0], 1);
    __builtin_amdgcn_s_setprio(0);
    phase_bar();
#pragma unroll
    for (int i = 0; i < 4; i++) {
      Ar[2 * i] = *(const bf16x8*)(pA0 + bo + (i + 4) * 1024);
      Ar[2 * i + 1] = *(const bf16x8*)(pA1 + bo + (i + 4) * 1024);
    }
    if (t + 2 < NT) stageB(0, t + 2, 0);
    phase_bar();
    __builtin_amdgcn_s_setprio(1);
    quad(Ar, Br1, &acc[4], 1);
    __builtin_amdgcn_s_setprio(0);
    phase_bar();
    if (t + 2 < NT) stageA(1, t + 2, 0);
    phase_bar();
    __builtin_amdgcn_s_setprio(1);
    quad(Ar, Br0, &acc[4], 0);
    __builtin_amdgcn_s_setprio(0);
    if (t + 2 < NT) {
      asm volatile("s_waitcnt vmcnt(4)" ::: "memory");
    } else {
      asm volatile("s_waitcnt vmcnt(0)" ::: "memory");
    }
    phase_bar();
  }

#pragma unroll
  for (int mf = 0; mf < 8; mf++) {
#pragma unroll
    for (int nf = 0; nf < 4; nf++) {
      const int n = n0 + wn * 64 + nf * 16 + r16;
      float bia = (EPI == EPI_PART) ? 0.f : bias[n];
#pragma unroll
      for (int reg = 0; reg < 4; reg++) {
        const int m = m0 + wm * 128 + mf * 16 + g * 4 + reg;
        float v = acc[mf][nf][reg] + bia;
        if constexpr (EPI == EPI_BF16) {
          outbz[(size_t)m * ldc + n] = f2bf(v);
        } else if constexpr (EPI == EPI_RESID) {
          outf[(size_t)m * ldc + n] = v + resid[(size_t)m * ldc + n];
        } else if constexpr (EPI == EPI_SILU) {
          float sv = v / (1.f + __expf(-v));
          outbz[(size_t)m * ldc + n] = f2bf(sv);
        } else if constexpr (EPI == EPI_MUL) {
          float hv = bf2f(outbz[(size_t)m * ldc + n]);
          outbz[(size_t)m * ldc + n] = f2bf(v * hv);
        } else {
          outbz[(size_t)m * ldc + n] = f2bf(v);
        }
      }
    }
  }
}

// ---------------- split-K reduce for w2 ----------------
__global__ __launch_bounds__(256) void reduce_k(const ushort* __restrict__ part,
                                                const float* __restrict__ b2,
                                                float* __restrict__ out) {
  int i = (blockIdx.x * 256 + threadIdx.x) * 8;
  int col = i & (DMODEL - 1);
  float s[8];
#pragma unroll
  for (int j = 0; j < 8; j++) s[j] = out[i + j] + b2[col + j];
#pragma unroll
  for (int z = 0; z < 4; z++) {
    bf16x8 v = *(const bf16x8*)(part + (size_t)z * 4194304 + i);
#pragma unroll
    for (int j = 0; j < 8; j++) s[j] += bf2f((ushort)v[j]);
  }
#pragma unroll
  for (int j = 0; j < 8; j++) out[i + j] = s[j];
}

// ======== Flash attention v2: 32x32 MFMA, swapped QK^T, in-reg softmax ======
// Block = 4 waves x 32 q-rows = 128 q. KVBLK = 64. One barrier/tile.
// S^T = mfma32(K, Q): lane q = l&31, kv = (r&3)+8*(r>>2)+4*(l>>5) per 32-chunk.
// O^T = mfma32(V^T, P^T): col = q = lane -> softmax state & rescale lane-local.
__global__ __launch_bounds__(256, 3) void flash2_k(const ushort* __restrict__ qkv,
                                                   ushort* __restrict__ att) {
  const int bid = blockIdx.x;
  const int head = (bid >> 4) & 31;
  const int rmap = bid & 15;
  const int qb = (bid & 256) ? (15 - rmap) : rmap;  // balance causal work
  const int kvh = head >> 2;
  const int tid = threadIdx.x;
  const int w = tid >> 6, l = tid & 63;
  const int h = l >> 5, q31 = l & 31;
  const int qw = qb * 128 + w * 32;
  const int qrow = qw + q31;

  __shared__ __align__(16) ushort lds[2][8192];  // [buf][ K 4096 | V^T 4096 ]

  bf16x8 qreg[4];
  {
    const ushort* qp = qkv + (size_t)qrow * 3072 + head * HD;
#pragma unroll
    for (int s = 0; s < 4; s++)
      qreg[s] = *(const bf16x8*)(qp + s * 16 + h * 8);
  }

  f32x16 oacc[2];
#pragma unroll
  for (int i = 0; i < 16; i++) { oacc[0][i] = 0.f; oacc[1][i] = 0.f; }
  float mreg = -1e30f, lsum = 0.f;

  const int nt = 2 * qb + 2;

  // staging geometry
  const int skv = tid >> 2;          // K: kv row
  const int sch = (tid & 3) * 2;     // K: chunk pair
  const int vkv = tid & 63;          // V: kv
  const int vd0 = (tid >> 6) * 16;   // V: d0

  const ushort* kg_base = qkv + DMODEL + kvh * HD;

  bf16x8 krA, krB, vrA, vrB;
  auto loadTile = [&](int jb) {
    const ushort* kg = kg_base + (size_t)jb * 64 * 3072;
    krA = *(const bf16x8*)(kg + (size_t)skv * 3072 + sch * 8);
    krB = *(const bf16x8*)(kg + (size_t)skv * 3072 + sch * 8 + 8);
    const ushort* vg = kg + 512;
    vrA = *(const bf16x8*)(vg + (size_t)vkv * 3072 + vd0);
    vrB = *(const bf16x8*)(vg + (size_t)vkv * 3072 + vd0 + 8);
  };
  auto writeTile = [&](int b) {
    ushort* kb = lds[b];
    *(bf16x8*)(kb + skv * 64 + ((sch ^ (skv & 7)) * 8)) = krA;
    *(bf16x8*)(kb + skv * 64 + (((sch + 1) ^ (skv & 7)) * 8)) = krB;
    ushort* vb = lds[b] + 4096;
#pragma unroll
    for (int i = 0; i < 8; i++) {
      int d = vd0 + i;
      vb[d * 64 + (((vkv >> 3) ^ (d & 7)) * 8) + (vkv & 7)] = (ushort)vrA[i];
    }
#pragma unroll
    for (int i = 0; i < 8; i++) {
      int d = vd0 + 8 + i;
      vb[d * 64 + (((vkv >> 3) ^ (d & 7)) * 8) + (vkv & 7)] = (ushort)vrB[i];
    }
  };

  loadTile(0);
  for (int jb = 0; jb < nt; ++jb) {
    const int b = jb & 1;
    writeTile(b);
    __syncthreads();
    if (jb + 1 < nt) loadTile(jb + 1);

    if (jb * 64 <= qw + 31) {  // warp has unmasked work
      const ushort* Kb = lds[b];
      const ushort* Vb = lds[b] + 4096;

      f32x16 sacc[2];
#pragma unroll
      for (int i = 0; i < 16; i++) { sacc[0][i] = 0.f; sacc[1][i] = 0.f; }
#pragma unroll
      for (int c = 0; c < 2; c++) {
        const int kvr = c * 32 + q31;
        const ushort* kp = Kb + kvr * 64;
        const int kx = kvr & 7;
#pragma unroll
        for (int s = 0; s < 4; s++) {
          bf16x8 kf = *(const bf16x8*)(kp + ((2 * s + h) ^ kx) * 8);
          sacc[c] = MFMA32(kf, qreg[s], sacc[c]);
        }
      }

      const bool diag = (jb * 64 + 63 > qw);
      if (diag) {
#pragma unroll
        for (int c = 0; c < 2; c++)
#pragma unroll
          for (int rg = 0; rg < 16; rg++) {
            int kvg = jb * 64 + c * 32 + (rg & 3) + 8 * (rg >> 2) + 4 * h;
            if (kvg > qrow) sacc[c][rg] = -1e30f;
          }
      }
      float tmax = sacc[0][0];
#pragma unroll
      for (int rg = 1; rg < 16; rg++) tmax = fmaxf(tmax, sacc[0][rg]);
#pragma unroll
      for (int rg = 0; rg < 16; rg++) tmax = fmaxf(tmax, sacc[1][rg]);
      tmax = fmaxf(tmax, __shfl_xor(tmax, 32));
      const float mn = fmaxf(mreg, tmax);
      const float resc = __expf((mreg - mn) * 0.125f);
      mreg = mn;
      float rsum = 0.f;
#pragma unroll
      for (int c = 0; c < 2; c++)
#pragma unroll
        for (int rg = 0; rg < 16; rg++) {
          float pv = __expf((sacc[c][rg] - mn) * 0.125f);
          sacc[c][rg] = pv;
          rsum += pv;
        }
      rsum += __shfl_xor(rsum, 32);
      lsum = lsum * resc + rsum;
      oacc[0] *= resc;
      oacc[1] *= resc;

      unsigned pw_[2][4][2];
#pragma unroll
      for (int c = 0; c < 2; c++)
#pragma unroll
        for (int rr = 0; rr < 4; rr++) {
          pw_[c][rr][0] = cvtpk(sacc[c][4 * rr + 0], sacc[c][4 * rr + 1]);
          pw_[c][rr][1] = cvtpk(sacc[c][4 * rr + 2], sacc[c][4 * rr + 3]);
        }

#pragma unroll
      for (int s = 0; s < 4; s++) {
        const int c = s >> 1, base = (s & 1) * 2;
        // keep = own-half words, send = partner-half words
        unsigned k0 = h ? pw_[c][base + 1][0] : pw_[c][base][0];
        unsigned k1 = h ? pw_[c][base + 1][1] : pw_[c][base][1];
        unsigned s0 = h ? pw_[c][base][0] : pw_[c][base + 1][0];
        unsigned s1 = h ? pw_[c][base][1] : pw_[c][base + 1][1];
        unsigned t0 = __shfl_xor(s0, 32);
        unsigned t1 = __shfl_xor(s1, 32);
        union { unsigned u[4]; bf16x8 v; } pf;
        pf.u[0] = h ? t0 : k0;
        pf.u[1] = h ? t1 : k1;
        pf.u[2] = h ? k0 : t0;
        pf.u[3] = h ? k1 : t1;
#pragma unroll
        for (int dt = 0; dt < 2; dt++) {
          const int d = dt * 32 + q31;
          bf16x8 vf =
              *(const bf16x8*)(Vb + d * 64 + ((2 * s + h) ^ (d & 7)) * 8);
          oacc[dt] = MFMA32(vf, pf.v, oacc[dt]);
        }
      }
    }
  }

  const float inv = 1.f / lsum;
  ushort* op = att + (size_t)qrow * DMODEL + head * HD;
#pragma unroll
  for (int dt = 0; dt < 2; dt++)
#pragma unroll
    for (int rr = 0; rr < 4; rr++) {
      const int d0 = dt * 32 + 8 * rr + 4 * h;
      unsigned lo = cvtpk(oacc[dt][4 * rr + 0] * inv, oacc[dt][4 * rr + 1] * inv);
      unsigned hi = cvtpk(oacc[dt][4 * rr + 2] * inv, oacc[dt][4 * rr + 3] * inv);
      uint2 v2;
      v2.x = lo;
      v2.y = hi;
      *(uint2*)(op + d0) = v2;
    }
}

extern "C" void kernel_launch(void* const* d_in, const int* in_sizes, int n_in,
                              void* d_out, int out_size, void* d_ws,
                              size_t ws_size, hipStream_t stream) {
  (void)in_sizes; (void)n_in; (void)out_size; (void)ws_size;
  const float* hidden = (const float*)d_in[0];
  const float* cosb = (const float*)d_in[1];
  const float* sinb = (const float*)d_in[2];
  const float* wq = (const float*)d_in[4];
  const float* bq = (const float*)d_in[5];
  const float* wk = (const float*)d_in[6];
  const float* bk = (const float*)d_in[7];
  const float* wv = (const float*)d_in[8];
  const float* bv = (const float*)d_in[9];
  const float* wo = (const float*)d_in[10];
  const float* bo = (const float*)d_in[11];
  const float* ln1 = (const float*)d_in[12];
  const float* ln2 = (const float*)d_in[13];
  const float* w1 = (const float*)d_in[16];
  const float* b1 = (const float*)d_in[17];
  const float* w2 = (const float*)d_in[18];
  const float* b2 = (const float*)d_in[19];
  const float* w3 = (const float*)d_in[20];
  const float* b3 = (const float*)d_in[21];
  float* out = (float*)d_out;

  char* ws = (char*)d_ws;
  ushort* part = (ushort*)ws;  // 32MB overlay on x1/qkv/att/x2 (dead by w2)
  ushort* x1 = (ushort*)ws;   ws += (size_t)S_LEN * DMODEL * 2;
  ushort* qkv = (ushort*)ws;  ws += (size_t)S_LEN * 3072 * 2;
  ushort* att = (ushort*)ws;  ws += (size_t)S_LEN * DMODEL * 2;
  ushort* x2 = (ushort*)ws;   ws += (size_t)S_LEN * DMODEL * 2;
  ushort* hbuf = (ushort*)ws; ws += (size_t)S_LEN * FFN_DIM * 2;
  ushort* wbuf = (ushort*)ws; ws += (size_t)FFN_DIM * DMODEL * 2;
  float* bqkv = (float*)ws;   ws += 3072 * 4;

  rmsnorm_k<<<S_LEN, 256, 0, stream>>>(hidden, ln1, x1);

  cvt_k<<<(2048 * 2048) / 2048, 256, 0, stream>>>(wq, wbuf);
  cvt_k<<<(512 * 2048) / 2048, 256, 0, stream>>>(wk, wbuf + 2048 * 2048);
  cvt_k<<<(512 * 2048) / 2048, 256, 0, stream>>>(wv, wbuf + 2560 * 2048);
  bias3_k<<<12, 256, 0, stream>>>(bq, bk, bv, bqkv);

  gemm256<EPI_BF16><<<dim3(8, 12), 512, 0, stream>>>(
      x1, DMODEL, wbuf, DMODEL, bqkv, nullptr, qkv, nullptr, 3072, DMODEL, 0,
      0);

  rope_k<<<(S_LEN * (NH + NKV) * 32) / 256, 256, 0, stream>>>(qkv, cosb, sinb);

  flash2_k<<<512, 256, 0, stream>>>(qkv, att);

  cvt_k<<<(2048 * 2048) / 2048, 256, 0, stream>>>(wo, wbuf);
  gemm256<EPI_RESID><<<dim3(8, 8), 512, 0, stream>>>(
      att, DMODEL, wbuf, DMODEL, bo, hidden, nullptr, out, DMODEL, DMODEL, 0,
      0);

  rmsnorm_k<<<S_LEN, 256, 0, stream>>>(out, ln2, x2);

  cvt_k<<<(FFN_DIM * 2048) / 2048, 256, 0, stream>>>(w1, wbuf);
  gemm256<EPI_SILU><<<dim3(8, 32), 512, 0, stream>>>(
      x2, DMODEL, wbuf, DMODEL, b1, nullptr, hbuf, nullptr, FFN_DIM, DMODEL, 0,
      0);

  cvt_k<<<(FFN_DIM * 2048) / 2048, 256, 0, stream>>>(w3, wbuf);
  gemm256<EPI_MUL><<<dim3(8, 32), 512, 0, stream>>>(
      x2, DMODEL, wbuf, DMODEL, b3, nullptr, hbuf, nullptr, FFN_DIM, DMODEL, 0,
      0);

  cvt_k<<<(DMODEL * FFN_DIM) / 2048, 256, 0, stream>>>(w2, wbuf);
  gemm256<EPI_PART><<<dim3(8, 8, 4), 512, 0, stream>>>(
      hbuf, FFN_DIM, wbuf, FFN_DIM, nullptr, nullptr, part, nullptr, DMODEL,
      DMODEL, DMODEL, (long long)S_LEN * DMODEL);
  reduce_k<<<(S_LEN * DMODEL) / 2048, 256, 0, stream>>>(part, b2, out);
}

// Round 5
// 425.288 us; speedup vs baseline: 2.9196x; 1.0869x over previous
//
#include <hip/hip_runtime.h>

#define S_LEN 2048
#define DMODEL 2048
#define NH 32
#define NKV 8
#define HD 64
#define FFN_DIM 8192

typedef __attribute__((ext_vector_type(4))) float f32x4;
typedef __attribute__((ext_vector_type(16))) float f32x16;
typedef __attribute__((ext_vector_type(8))) short bf16x8;

#define MFMA(a, b, c) __builtin_amdgcn_mfma_f32_16x16x32_bf16(a, b, c, 0, 0, 0)
#define MFMA32(a, b, c) __builtin_amdgcn_mfma_f32_32x32x16_bf16(a, b, c, 0, 0, 0)

__device__ __forceinline__ ushort f2bf(float f) {
  unsigned u = __float_as_uint(f);
  unsigned r = (u + 0x7fffu + ((u >> 16) & 1u)) >> 16;
  return (ushort)r;
}
__device__ __forceinline__ float bf2f(ushort s) {
  return __uint_as_float(((unsigned)s) << 16);
}
__device__ __forceinline__ unsigned cvtpk(float a, float b) {
  unsigned r;
  asm("v_cvt_pk_bf16_f32 %0, %1, %2" : "=v"(r) : "v"(a), "v"(b));
  return r;
}

__device__ __forceinline__ void gload16(const void* g, void* l) {
  __builtin_amdgcn_global_load_lds(
      (const __attribute__((address_space(1))) void*)g,
      (__attribute__((address_space(3))) void*)l, 16, 0, 0);
}

// ---------------- weight conversion ----------------
__global__ __launch_bounds__(256) void cvt_k(const float* __restrict__ in,
                                             ushort* __restrict__ out) {
  int i = blockIdx.x * 256 + threadIdx.x;
  f32x4 a = ((const f32x4*)in)[i * 2];
  f32x4 b = ((const f32x4*)in)[i * 2 + 1];
  bf16x8 r;
#pragma unroll
  for (int j = 0; j < 4; j++) r[j] = (short)f2bf(a[j]);
#pragma unroll
  for (int j = 0; j < 4; j++) r[4 + j] = (short)f2bf(b[j]);
  ((bf16x8*)out)[i] = r;
}

// one row per block; q|k|v concat -> [3072][2048] bf16
__global__ __launch_bounds__(256) void cvt_qkv_k(const float* __restrict__ wq,
                                                 const float* __restrict__ wk,
                                                 const float* __restrict__ wv,
                                                 ushort* __restrict__ dst) {
  int row = blockIdx.x;
  const float* src;
  if (row < 2048) src = wq + (size_t)row * DMODEL;
  else if (row < 2560) src = wk + (size_t)(row - 2048) * DMODEL;
  else src = wv + (size_t)(row - 2560) * DMODEL;
  int i = threadIdx.x * 8;
  f32x4 a = *(const f32x4*)(src + i);
  f32x4 b = *(const f32x4*)(src + i + 4);
  bf16x8 r;
#pragma unroll
  for (int j = 0; j < 4; j++) r[j] = (short)f2bf(a[j]);
#pragma unroll
  for (int j = 0; j < 4; j++) r[4 + j] = (short)f2bf(b[j]);
  *(bf16x8*)(dst + (size_t)row * DMODEL + i) = r;
}

__global__ __launch_bounds__(256) void bias3_k(const float* __restrict__ a,
                                               const float* __restrict__ b,
                                               const float* __restrict__ c,
                                               float* __restrict__ out) {
  int i = blockIdx.x * 256 + threadIdx.x;
  float v;
  if (i < 2048) v = a[i];
  else if (i < 2560) v = b[i - 2048];
  else v = c[i - 2560];
  out[i] = v;
}

// ---------------- RMSNorm ----------------
__global__ __launch_bounds__(256) void rmsnorm_k(const float* __restrict__ in,
                                                 const float* __restrict__ w,
                                                 ushort* __restrict__ out) {
  const int row = blockIdx.x;
  const int tid = threadIdx.x;
  const float* x = in + (size_t)row * DMODEL;
  f32x4 v0 = *(const f32x4*)(x + tid * 8);
  f32x4 v1 = *(const f32x4*)(x + tid * 8 + 4);
  float ss = v0[0] * v0[0] + v0[1] * v0[1] + v0[2] * v0[2] + v0[3] * v0[3] +
             v1[0] * v1[0] + v1[1] * v1[1] + v1[2] * v1[2] + v1[3] * v1[3];
#pragma unroll
  for (int off = 32; off; off >>= 1) ss += __shfl_xor(ss, off, 64);
  __shared__ float red[4];
  if ((tid & 63) == 0) red[tid >> 6] = ss;
  __syncthreads();
  float tot = red[0] + red[1] + red[2] + red[3];
  float inv = rsqrtf(tot * (1.f / DMODEL) + 1e-5f);
#pragma unroll
  for (int i = 0; i < 8; i++) {
    int c = tid * 8 + i;
    float val = (i < 4) ? v0[i] : v1[i - 4];
    out[(size_t)row * DMODEL + c] = f2bf(w[c] * val * inv);
  }
}

// ---------------- RoPE ----------------
__global__ __launch_bounds__(256) void rope_k(ushort* __restrict__ qkv,
                                              const float* __restrict__ cs,
                                              const float* __restrict__ sn) {
  int idx = blockIdx.x * 256 + threadIdx.x;
  int d = idx & 31;
  int t = idx >> 5;
  int head = t % (NH + NKV);
  int s = t / (NH + NKV);
  int col = (head < NH) ? head * HD : DMODEL + (head - NH) * HD;
  ushort* p = qkv + (size_t)s * 3072 + col;
  float lo = bf2f(p[d]), hi = bf2f(p[d + 32]);
  float c = cs[s * HD + d], si = sn[s * HD + d];
  p[d] = f2bf(lo * c - hi * si);
  p[d + 32] = f2bf(hi * c + lo * si);
}

// ======== 256x256 8-phase GEMM: C[M,N] = A[M,K] @ B[N,K]^T (+ epilogue) ======
enum { EPI_BF16 = 0, EPI_RESID = 1, EPI_SILU = 2, EPI_MUL = 3, EPI_PART = 4 };

__device__ __forceinline__ void quad(const bf16x8* Arr, const bf16x8* BR,
                                     f32x4 (*accr)[4], int qn) {
#pragma unroll
  for (int i = 0; i < 4; i++)
#pragma unroll
    for (int j = 0; j < 2; j++)
#pragma unroll
      for (int ks = 0; ks < 2; ks++)
        accr[i][qn * 2 + j] =
            MFMA(Arr[2 * i + ks], BR[2 * j + ks], accr[i][qn * 2 + j]);
}

template <int EPI>
__global__ __launch_bounds__(512, 2) void gemm256(
    const ushort* __restrict__ A, int lda, const ushort* __restrict__ B,
    int ldb, const float* __restrict__ bias, const float* __restrict__ resid,
    ushort* __restrict__ outb, float* __restrict__ outf, int ldc, int K,
    int kspan, long long opart) {
  __shared__ __align__(16) ushort lds[65536];
  const int tid = threadIdx.x;
  const int l = tid & 63, w = tid >> 6;
  const int g = l >> 4, r16 = l & 15;
  const int wm = w >> 2, wn = w & 3;

  int nwg = gridDim.x * gridDim.y;
  int bid = blockIdx.y * gridDim.x + blockIdx.x;
  bid = (bid & 7) * (nwg >> 3) + (bid >> 3);  // XCD swizzle (nwg%8==0)
  const int m0 = (bid % gridDim.x) * 256;
  const int n0 = (bid / gridDim.x) * 256;
  const int z = blockIdx.z;

  const ushort* Ag = A + (size_t)z * kspan + (size_t)m0 * lda;
  const ushort* Bg = B + (size_t)z * kspan + (size_t)n0 * ldb;
  ushort* outbz = outb;
  if (EPI == EPI_PART) outbz = outb + (size_t)z * opart;

  const int NT = K >> 6;

  const int stgRow = w * 8 + (l >> 3);
  const int stgCol = ((l & 7) ^ (l >> 3)) * 8;

  const int xa = (r16 & 7) << 4;
  const int c0 = ((g * 16) ^ xa) >> 1;
  const int c1 = c0 ^ 32;
  const int slotA = wm ? 3 : 1;
  const int slotB = (wn >> 1) ? 2 : 0;
  const ushort* pA0 = lds + slotA * 8192 + r16 * 64 + c0;
  const ushort* pA1 = lds + slotA * 8192 + r16 * 64 + c1;
  const ushort* pB0 = lds + slotB * 8192 + ((wn & 1) * 64 + r16) * 64 + c0;
  const ushort* pB1 = lds + slotB * 8192 + ((wn & 1) * 64 + r16) * 64 + c1;

  f32x4 acc[8][4];
#pragma unroll
  for (int i = 0; i < 8; i++)
#pragma unroll
    for (int j = 0; j < 4; j++) acc[i][j] = (f32x4){0, 0, 0, 0};

  auto stageA = [&](int slot, int tile, int hf) {
    ushort* dst = lds + ((tile & 1) * 32768 + slot * 8192 + w * 512);
    const ushort* src =
        Ag + (size_t)(hf * 128 + stgRow) * lda + tile * 64 + stgCol;
    gload16(src, dst);
    gload16(src + (size_t)64 * lda, dst + 4096);
  };
  auto stageB = [&](int slot, int tile, int hf) {
    ushort* dst = lds + ((tile & 1) * 32768 + slot * 8192 + w * 512);
    const ushort* src =
        Bg + (size_t)(hf * 128 + stgRow) * ldb + tile * 64 + stgCol;
    gload16(src, dst);
    gload16(src + (size_t)64 * ldb, dst + 4096);
  };

  // prologue: tile0 all 4 slots + tile1 B0,A0; drain to 4 outstanding
  stageB(0, 0, 0);
  stageA(1, 0, 0);
  stageB(2, 0, 1);
  stageA(3, 0, 1);
  stageB(0, 1, 0);
  stageA(1, 1, 0);
  asm volatile("s_waitcnt vmcnt(4)" ::: "memory");
  __builtin_amdgcn_s_barrier();

  bf16x8 Ar[8], Br0[4], Br1[4];

  for (int t = 0; t < NT; ++t) {
    const int bo = (t & 1) * 32768;
    // ---- q0: read A-lo + B-lo; stage B1(t+1); MFMA quad(lo,0)
#pragma unroll
    for (int i = 0; i < 4; i++) {
      Ar[2 * i] = *(const bf16x8*)(pA0 + bo + i * 1024);
      Ar[2 * i + 1] = *(const bf16x8*)(pA1 + bo + i * 1024);
    }
#pragma unroll
    for (int j = 0; j < 2; j++) {
      Br0[2 * j] = *(const bf16x8*)(pB0 + bo + j * 1024);
      Br0[2 * j + 1] = *(const bf16x8*)(pB1 + bo + j * 1024);
    }
    if (t + 1 < NT) stageB(2, t + 1, 1);
    __builtin_amdgcn_s_barrier();
    __builtin_amdgcn_s_setprio(1);
    quad(Ar, Br0, &acc[0], 0);
    __builtin_amdgcn_s_setprio(0);
    __builtin_amdgcn_s_barrier();
    // ---- q1: read B-hi; stage A1(t+1); MFMA quad(lo,1)
#pragma unroll
    for (int j = 0; j < 2; j++) {
      Br1[2 * j] = *(const bf16x8*)(pB0 + bo + (j + 2) * 1024);
      Br1[2 * j + 1] = *(const bf16x8*)(pB1 + bo + (j + 2) * 1024);
    }
    if (t + 1 < NT) stageA(3, t + 1, 1);
    __builtin_amdgcn_s_barrier();
    __builtin_amdgcn_s_setprio(1);
    quad(Ar, Br1, &acc[0], 1);
    __builtin_amdgcn_s_setprio(0);
    __builtin_amdgcn_s_barrier();
    // ---- q2: read A-hi; stage B0(t+2); MFMA quad(hi,1)
#pragma unroll
    for (int i = 0; i < 4; i++) {
      Ar[2 * i] = *(const bf16x8*)(pA0 + bo + (i + 4) * 1024);
      Ar[2 * i + 1] = *(const bf16x8*)(pA1 + bo + (i + 4) * 1024);
    }
    if (t + 2 < NT) stageB(0, t + 2, 0);
    __builtin_amdgcn_s_barrier();
    __builtin_amdgcn_s_setprio(1);
    quad(Ar, Br1, &acc[4], 1);
    __builtin_amdgcn_s_setprio(0);
    __builtin_amdgcn_s_barrier();
    // ---- q3: stage A0(t+2); MFMA quad(hi,0); counted vmcnt
    if (t + 2 < NT) stageA(1, t + 2, 0);
    __builtin_amdgcn_s_barrier();
    __builtin_amdgcn_s_setprio(1);
    quad(Ar, Br0, &acc[4], 0);
    __builtin_amdgcn_s_setprio(0);
    if (t + 2 < NT) {
      asm volatile("s_waitcnt vmcnt(4)" ::: "memory");
    } else {
      asm volatile("s_waitcnt vmcnt(0)" ::: "memory");
    }
    __builtin_amdgcn_s_barrier();
  }

  // epilogue
#pragma unroll
  for (int mf = 0; mf < 8; mf++) {
#pragma unroll
    for (int nf = 0; nf < 4; nf++) {
      const int n = n0 + wn * 64 + nf * 16 + r16;
      float bia = (EPI == EPI_PART) ? 0.f : bias[n];
#pragma unroll
      for (int reg = 0; reg < 4; reg++) {
        const int m = m0 + wm * 128 + mf * 16 + g * 4 + reg;
        float v = acc[mf][nf][reg] + bia;
        if constexpr (EPI == EPI_BF16) {
          outbz[(size_t)m * ldc + n] = f2bf(v);
        } else if constexpr (EPI == EPI_RESID) {
          outf[(size_t)m * ldc + n] = v + resid[(size_t)m * ldc + n];
        } else if constexpr (EPI == EPI_SILU) {
          float sv = v / (1.f + __expf(-v));
          outbz[(size_t)m * ldc + n] = f2bf(sv);
        } else if constexpr (EPI == EPI_MUL) {
          float hv = bf2f(outbz[(size_t)m * ldc + n]);
          outbz[(size_t)m * ldc + n] = f2bf(v * hv);
        } else {
          outbz[(size_t)m * ldc + n] = f2bf(v);
        }
      }
    }
  }
}

// ---------------- split-K reduce (MODE 0: bf16 out; 1: f32 out + resid) ----
template <int MODE>
__global__ __launch_bounds__(256) void reduce2_k(
    const ushort* __restrict__ part, long long pstride, int nz,
    const float* __restrict__ bias, int ncol, const float* __restrict__ resid,
    float* __restrict__ outf, ushort* __restrict__ outb) {
  long long i = (long long)(blockIdx.x * 256 + threadIdx.x) * 8;
  int col = (int)(i % ncol);
  float s[8];
#pragma unroll
  for (int j = 0; j < 8; j++) s[j] = bias[col + j];
  for (int zz = 0; zz < nz; zz++) {
    bf16x8 v = *(const bf16x8*)(part + zz * pstride + i);
#pragma unroll
    for (int j = 0; j < 8; j++) s[j] += bf2f((ushort)v[j]);
  }
  if constexpr (MODE == 1) {
#pragma unroll
    for (int j = 0; j < 8; j++) outf[i + j] = s[j] + resid[i + j];
  } else {
    bf16x8 r;
#pragma unroll
    for (int j = 0; j < 8; j++) r[j] = (short)f2bf(s[j]);
    *(bf16x8*)(outb + i) = r;
  }
}

// ======== Flash attention: 32x32 MFMA, swapped QK^T, in-reg softmax ========
__global__ __launch_bounds__(256, 3) void flash2_k(const ushort* __restrict__ qkv,
                                                   ushort* __restrict__ att) {
  const int bid = blockIdx.x;
  const int head = (bid >> 4) & 31;
  const int rmap = bid & 15;
  const int qb = (bid & 256) ? (15 - rmap) : rmap;
  const int kvh = head >> 2;
  const int tid = threadIdx.x;
  const int w = tid >> 6, l = tid & 63;
  const int h = l >> 5, q31 = l & 31;
  const int qw = qb * 128 + w * 32;
  const int qrow = qw + q31;

  __shared__ __align__(16) ushort lds[2][8192];

  bf16x8 qreg[4];
  {
    const ushort* qp = qkv + (size_t)qrow * 3072 + head * HD;
#pragma unroll
    for (int s = 0; s < 4; s++)
      qreg[s] = *(const bf16x8*)(qp + s * 16 + h * 8);
  }

  f32x16 oacc[2];
#pragma unroll
  for (int i = 0; i < 16; i++) { oacc[0][i] = 0.f; oacc[1][i] = 0.f; }
  float mreg = -1e30f, lsum = 0.f;

  const int nt = 2 * qb + 2;

  const int skv = tid >> 2;
  const int sch = (tid & 3) * 2;
  const int vkv = tid & 63;
  const int vd0 = (tid >> 6) * 16;

  const ushort* kg_base = qkv + DMODEL + kvh * HD;

  bf16x8 krA, krB, vrA, vrB;
  auto loadTile = [&](int jb) {
    const ushort* kg = kg_base + (size_t)jb * 64 * 3072;
    krA = *(const bf16x8*)(kg + (size_t)skv * 3072 + sch * 8);
    krB = *(const bf16x8*)(kg + (size_t)skv * 3072 + sch * 8 + 8);
    const ushort* vg = kg + 512;
    vrA = *(const bf16x8*)(vg + (size_t)vkv * 3072 + vd0);
    vrB = *(const bf16x8*)(vg + (size_t)vkv * 3072 + vd0 + 8);
  };
  auto writeTile = [&](int b) {
    ushort* kb = lds[b];
    *(bf16x8*)(kb + skv * 64 + ((sch ^ (skv & 7)) * 8)) = krA;
    *(bf16x8*)(kb + skv * 64 + (((sch + 1) ^ (skv & 7)) * 8)) = krB;
    ushort* vb = lds[b] + 4096;
#pragma unroll
    for (int i = 0; i < 8; i++) {
      int d = vd0 + i;
      vb[d * 64 + (((vkv >> 3) ^ (d & 7)) * 8) + (vkv & 7)] = (ushort)vrA[i];
    }
#pragma unroll
    for (int i = 0; i < 8; i++) {
      int d = vd0 + 8 + i;
      vb[d * 64 + (((vkv >> 3) ^ (d & 7)) * 8) + (vkv & 7)] = (ushort)vrB[i];
    }
  };

  loadTile(0);
  for (int jb = 0; jb < nt; ++jb) {
    const int b = jb & 1;
    writeTile(b);
    __syncthreads();
    if (jb + 1 < nt) loadTile(jb + 1);

    if (jb * 64 <= qw + 31) {
      const ushort* Kb = lds[b];
      const ushort* Vb = lds[b] + 4096;

      f32x16 sacc[2];
#pragma unroll
      for (int i = 0; i < 16; i++) { sacc[0][i] = 0.f; sacc[1][i] = 0.f; }
#pragma unroll
      for (int c = 0; c < 2; c++) {
        const int kvr = c * 32 + q31;
        const ushort* kp = Kb + kvr * 64;
        const int kx = kvr & 7;
#pragma unroll
        for (int s = 0; s < 4; s++) {
          bf16x8 kf = *(const bf16x8*)(kp + ((2 * s + h) ^ kx) * 8);
          sacc[c] = MFMA32(kf, qreg[s], sacc[c]);
        }
      }

      const bool diag = (jb * 64 + 63 > qw);
      if (diag) {
#pragma unroll
        for (int c = 0; c < 2; c++)
#pragma unroll
          for (int rg = 0; rg < 16; rg++) {
            int kvg = jb * 64 + c * 32 + (rg & 3) + 8 * (rg >> 2) + 4 * h;
            if (kvg > qrow) sacc[c][rg] = -1e30f;
          }
      }
      float tmax = sacc[0][0];
#pragma unroll
      for (int rg = 1; rg < 16; rg++) tmax = fmaxf(tmax, sacc[0][rg]);
#pragma unroll
      for (int rg = 0; rg < 16; rg++) tmax = fmaxf(tmax, sacc[1][rg]);
      tmax = fmaxf(tmax, __shfl_xor(tmax, 32));
      const float mn = fmaxf(mreg, tmax);
      const float resc = __expf((mreg - mn) * 0.125f);
      mreg = mn;
      float rsum = 0.f;
#pragma unroll
      for (int c = 0; c < 2; c++)
#pragma unroll
        for (int rg = 0; rg < 16; rg++) {
          float pv = __expf((sacc[c][rg] - mn) * 0.125f);
          sacc[c][rg] = pv;
          rsum += pv;
        }
      rsum += __shfl_xor(rsum, 32);
      lsum = lsum * resc + rsum;
      oacc[0] *= resc;
      oacc[1] *= resc;

      unsigned pw_[2][4][2];
#pragma unroll
      for (int c = 0; c < 2; c++)
#pragma unroll
        for (int rr = 0; rr < 4; rr++) {
          pw_[c][rr][0] = cvtpk(sacc[c][4 * rr + 0], sacc[c][4 * rr + 1]);
          pw_[c][rr][1] = cvtpk(sacc[c][4 * rr + 2], sacc[c][4 * rr + 3]);
        }

#pragma unroll
      for (int s = 0; s < 4; s++) {
        const int c = s >> 1, base = (s & 1) * 2;
        unsigned k0 = h ? pw_[c][base + 1][0] : pw_[c][base][0];
        unsigned k1 = h ? pw_[c][base + 1][1] : pw_[c][base][1];
        unsigned s0 = h ? pw_[c][base][0] : pw_[c][base + 1][0];
        unsigned s1 = h ? pw_[c][base][1] : pw_[c][base + 1][1];
        unsigned t0 = __shfl_xor(s0, 32);
        unsigned t1 = __shfl_xor(s1, 32);
        union { unsigned u[4]; bf16x8 v; } pf;
        pf.u[0] = h ? t0 : k0;
        pf.u[1] = h ? t1 : k1;
        pf.u[2] = h ? k0 : t0;
        pf.u[3] = h ? k1 : t1;
#pragma unroll
        for (int dt = 0; dt < 2; dt++) {
          const int d = dt * 32 + q31;
          bf16x8 vf =
              *(const bf16x8*)(Vb + d * 64 + ((2 * s + h) ^ (d & 7)) * 8);
          oacc[dt] = MFMA32(vf, pf.v, oacc[dt]);
        }
      }
    }
  }

  const float inv = 1.f / lsum;
  ushort* op = att + (size_t)qrow * DMODEL + head * HD;
#pragma unroll
  for (int dt = 0; dt < 2; dt++)
#pragma unroll
    for (int rr = 0; rr < 4; rr++) {
      const int d0 = dt * 32 + 8 * rr + 4 * h;
      unsigned lo = cvtpk(oacc[dt][4 * rr + 0] * inv, oacc[dt][4 * rr + 1] * inv);
      unsigned hi = cvtpk(oacc[dt][4 * rr + 2] * inv, oacc[dt][4 * rr + 3] * inv);
      uint2 v2;
      v2.x = lo;
      v2.y = hi;
      *(uint2*)(op + d0) = v2;
    }
}

extern "C" void kernel_launch(void* const* d_in, const int* in_sizes, int n_in,
                              void* d_out, int out_size, void* d_ws,
                              size_t ws_size, hipStream_t stream) {
  (void)in_sizes; (void)n_in; (void)out_size; (void)ws_size;
  const float* hidden = (const float*)d_in[0];
  const float* cosb = (const float*)d_in[1];
  const float* sinb = (const float*)d_in[2];
  const float* wq = (const float*)d_in[4];
  const float* bq = (const float*)d_in[5];
  const float* wk = (const float*)d_in[6];
  const float* bk = (const float*)d_in[7];
  const float* wv = (const float*)d_in[8];
  const float* bv = (const float*)d_in[9];
  const float* wo = (const float*)d_in[10];
  const float* bo = (const float*)d_in[11];
  const float* ln1 = (const float*)d_in[12];
  const float* ln2 = (const float*)d_in[13];
  const float* w1 = (const float*)d_in[16];
  const float* b1 = (const float*)d_in[17];
  const float* w2 = (const float*)d_in[18];
  const float* b2 = (const float*)d_in[19];
  const float* w3 = (const float*)d_in[20];
  const float* b3 = (const float*)d_in[21];
  float* out = (float*)d_out;

  char* ws = (char*)d_ws;
  ushort* x1 = (ushort*)ws;   ws += (size_t)S_LEN * DMODEL * 2;   // 8.4MB
  ushort* qkv = (ushort*)ws;  ws += (size_t)S_LEN * 3072 * 2;     // 12.6MB
  ushort* att = (ushort*)ws;  ws += (size_t)S_LEN * DMODEL * 2;   // 8.4MB
  ushort* x2 = (ushort*)ws;   ws += (size_t)S_LEN * DMODEL * 2;   // 8.4MB
  ushort* hbuf = (ushort*)ws; ws += (size_t)S_LEN * FFN_DIM * 2;  // 33.5MB
  ushort* wbuf = (ushort*)ws; ws += (size_t)FFN_DIM * DMODEL * 2; // 33.5MB
  float* bqkv = (float*)ws;   ws += 3072 * 4;

  // partial overlays on dead regions (liveness-checked):
  ushort* partQ = att;  // QKV partials (2 x 12.6MB) over att+x2+hbuf
  ushort* partO = x2;   // O-proj partials (4 x 8.4MB) over x2+hbuf
  ushort* partW = x1;   // w2 partials (4 x 8.4MB) over x1+qkv+att+x2

  // 1. RMSNorm -> x1
  rmsnorm_k<<<S_LEN, 256, 0, stream>>>(hidden, ln1, x1);

  // 2. weights: QKV concat -> wbuf; biases -> bqkv
  cvt_qkv_k<<<3072, 256, 0, stream>>>(wq, wk, wv, wbuf);
  bias3_k<<<12, 256, 0, stream>>>(bq, bk, bv, bqkv);

  // 3. QKV GEMM split-K=2 -> partials -> qkv
  gemm256<EPI_PART><<<dim3(8, 12, 2), 512, 0, stream>>>(
      x1, DMODEL, wbuf, DMODEL, nullptr, nullptr, partQ, nullptr, 3072, 1024,
      1024, (long long)S_LEN * 3072);
  reduce2_k<0><<<(S_LEN * 3072) / 2048, 256, 0, stream>>>(
      partQ, (long long)S_LEN * 3072, 2, bqkv, 3072, nullptr, nullptr, qkv);

  // 4. RoPE
  rope_k<<<(S_LEN * (NH + NKV) * 32) / 256, 256, 0, stream>>>(qkv, cosb, sinb);

  // 5. Flash attention -> att
  flash2_k<<<512, 256, 0, stream>>>(qkv, att);

  // 6. O-proj split-K=4 -> partials -> out (f32, + hidden resid)
  cvt_k<<<(2048 * 2048) / 2048, 256, 0, stream>>>(wo, wbuf);
  gemm256<EPI_PART><<<dim3(8, 8, 4), 512, 0, stream>>>(
      att, DMODEL, wbuf, DMODEL, nullptr, nullptr, partO, nullptr, DMODEL, 512,
      512, (long long)S_LEN * DMODEL);
  reduce2_k<1><<<(S_LEN * DMODEL) / 2048, 256, 0, stream>>>(
      partO, (long long)S_LEN * DMODEL, 4, bo, DMODEL, hidden, out, nullptr);

  // 7. RMSNorm2 -> x2
  rmsnorm_k<<<S_LEN, 256, 0, stream>>>(out, ln2, x2);

  // 8. h = silu(x2 @ w1^T + b1)
  cvt_k<<<(FFN_DIM * 2048) / 2048, 256, 0, stream>>>(w1, wbuf);
  gemm256<EPI_SILU><<<dim3(8, 32), 512, 0, stream>>>(
      x2, DMODEL, wbuf, DMODEL, b1, nullptr, hbuf, nullptr, FFN_DIM, DMODEL, 0,
      0);

  // 9. h *= (x2 @ w3^T + b3)
  cvt_k<<<(FFN_DIM * 2048) / 2048, 256, 0, stream>>>(w3, wbuf);
  gemm256<EPI_MUL><<<dim3(8, 32), 512, 0, stream>>>(
      x2, DMODEL, wbuf, DMODEL, b3, nullptr, hbuf, nullptr, FFN_DIM, DMODEL, 0,
      0);

  // 10. w2 split-K=4 -> partials -> out (f32, + out resid)
  cvt_k<<<(DMODEL * FFN_DIM) / 2048, 256, 0, stream>>>(w2, wbuf);
  gemm256<EPI_PART><<<dim3(8, 8, 4), 512, 0, stream>>>(
      hbuf, FFN_DIM, wbuf, FFN_DIM, nullptr, nullptr, partW, nullptr, DMODEL,
      DMODEL, DMODEL, (long long)S_LEN * DMODEL);
  reduce2_k<1><<<(S_LEN * DMODEL) / 2048, 256, 0, stream>>>(
      partW, (long long)S_LEN * DMODEL, 4, b2, DMODEL, out, out, nullptr);
}